// Round 1
// baseline (518.645 us; speedup 1.0000x reference)
//
#include <hip/hip_runtime.h>

// MultiHeadAttention: B=2, S=2048, D=1024, H=16, HD=64, scores MULTIPLIED by 64.
// Round 8: proj re-tiled 64x128 (grid 512, LDS 48 KiB -> 2 blocks/CU resident,
// was 1) to hide the per-k-iter vmcnt drain; flash gains T14 async-STAGE split
// (prefetch next K/V tile to regs during compute, ds_write after the read
// barrier) so L2 latency hides under QK^T+softmax+PV.
// LDS image: row r, logical chunk c stored at col (c ^ (r&7)) -- 2-way banks (free).
// Workspace 73 MiB: 0 qh_hi | 8 qh_lo | 16 kh_hi | 24 kh_lo | 32 vhT | 40 vh
//   | 48 xh | 56 xl | 64 Wh | 66 Wl ; Op aliases 40..72 ; 72 ml.

typedef _Float16 half4 __attribute__((ext_vector_type(4)));
typedef _Float16 half8 __attribute__((ext_vector_type(8)));
typedef float floatx4 __attribute__((ext_vector_type(4)));

#define MFMA_F16(a, b, c) __builtin_amdgcn_mfma_f32_16x16x32_f16((a), (b), (c), 0, 0, 0)

constexpr int SEQ = 2048;
constexpr int DM = 1024;
constexpr int NH = 16;
constexpr int HD = 64;
// 64 * log2(e): fold score scale + base-2 conversion into Q projection
constexpr float QSCALE = 92.33248261689366f;

// async 16B/lane global->LDS copy; LDS dest = wave-uniform base + lane*16
__device__ __forceinline__ void gl2lds16(const _Float16* g, _Float16* l) {
  __builtin_amdgcn_global_load_lds(
      (const __attribute__((address_space(1))) void*)g,
      (__attribute__((address_space(3))) void*)l, 16, 0, 0);
}

__device__ inline void split4(const float4 f, half4& h, half4& l) {
  h[0] = (_Float16)f.x; l[0] = (_Float16)(f.x - (float)h[0]);
  h[1] = (_Float16)f.y; l[1] = (_Float16)(f.y - (float)h[1]);
  h[2] = (_Float16)f.z; l[2] = (_Float16)(f.z - (float)h[2]);
  h[3] = (_Float16)f.w; l[3] = (_Float16)(f.w - (float)h[3]);
}

// ---------------- convert: fp32 -> fp16 hi (+lo) ----------------
// blocks 0..4095: x (4M floats); blocks 4096..5119: W (1M floats)
__global__ __launch_bounds__(256) void convert_kernel(
    const float* __restrict__ x, const float* __restrict__ W,
    _Float16* __restrict__ xh, _Float16* __restrict__ xl,
    _Float16* __restrict__ Wh, _Float16* __restrict__ Wl, int do_lo)
{
  if (blockIdx.x < 4096) {
    int idx = blockIdx.x * 256 + threadIdx.x;
    float4 f = ((const float4*)x)[idx];
    half4 h, l; split4(f, h, l);
    *(half4*)(xh + (size_t)idx * 4) = h;
    if (do_lo) *(half4*)(xl + (size_t)idx * 4) = l;
  } else {
    int idx = (blockIdx.x - 4096) * 256 + threadIdx.x;
    float4 f = ((const float4*)W)[idx];
    half4 h, l; split4(f, h, l);
    *(half4*)(Wh + (size_t)idx * 4) = h;
    if (do_lo) *(half4*)(Wl + (size_t)idx * 4) = l;
  }
}

// ---------------- projection GEMM: y = A @ B^T (pre-converted fp16) ---------
// 64x128 tile (BM=64, BN=128), BK=64, global_load_lds staging, XOR image.
// Grid (64,8) = 512 blocks, LDS 48 KiB -> 2 blocks/CU co-resident so one
// block's MFMA covers the other's staging drain (was 256 blocks / 1 per CU).
// three=1: 3-term split-fp16, writes yh+yl; three=0: single-term, yh only.
__global__ __launch_bounds__(256, 2) void proj_kernel(
    const _Float16* __restrict__ Ahg, const _Float16* __restrict__ Alg,
    const _Float16* __restrict__ Bhg, const _Float16* __restrict__ Blg,
    _Float16* __restrict__ yh, _Float16* __restrict__ yl,
    float scale, int three)
{
  __shared__ __align__(16) _Float16 Ahs[64][64];
  __shared__ __align__(16) _Float16 Als[64][64];
  __shared__ __align__(16) _Float16 Bhs[128][64];
  __shared__ __align__(16) _Float16 Bls[128][64];

  const int tid = threadIdx.x;
  const int bm = blockIdx.x;          // 0..63 (M=4096/64)
  const int bn = blockIdx.y;          // 0..7  (N=1024/128)
  const int lane = tid & 63, l15 = lane & 15, quad = lane >> 4;
  const int w = tid >> 6, wm = w >> 1, wn = w & 1;   // wave tile 32x64

  // staging: lane L -> row-in-group L>>3, logical chunk (L&7)^(L>>3) -> XOR image
  const int r8 = lane >> 3;
  const int cp8 = ((lane & 7) ^ r8) * 8;

  floatx4 acc[2][4];
  #pragma unroll
  for (int mt = 0; mt < 2; mt++)
    #pragma unroll
    for (int nt = 0; nt < 4; nt++)
      acc[mt][nt] = (floatx4){0.f, 0.f, 0.f, 0.f};

  for (int kk = 0; kk < DM; kk += 64) {
    __syncthreads();                          // prior tile's reads complete
    // A: 8 groups per array (64 rows), 2 per wave
    #pragma unroll
    for (int i = 0; i < 2; i++) {
      const int g = w * 2 + i;
      const size_t ga = (size_t)(bm * 64 + g * 8 + r8) * DM + kk + cp8;
      gl2lds16(Ahg + ga, &Ahs[0][0] + g * 512);
      if (three) gl2lds16(Alg + ga, &Als[0][0] + g * 512);
    }
    // B: 16 groups per array (128 rows), 4 per wave
    #pragma unroll
    for (int i = 0; i < 4; i++) {
      const int g = w * 4 + i;
      const size_t gb = (size_t)(bn * 128 + g * 8 + r8) * DM + kk + cp8;
      gl2lds16(Bhg + gb, &Bhs[0][0] + g * 512);
      if (three) gl2lds16(Blg + gb, &Bls[0][0] + g * 512);
    }
    __syncthreads();                          // vmcnt(0) drain: tile visible

    #pragma unroll
    for (int kc = 0; kc < 2; kc++) {
      const int swz = ((kc * 4 + quad) ^ (l15 & 7)) * 8;
      half8 ah[2], al[2], bh_[4], bl[4];
      #pragma unroll
      for (int mt = 0; mt < 2; mt++) {
        ah[mt] = *(const half8*)&Ahs[wm * 32 + mt * 16 + l15][swz];
        if (three) al[mt] = *(const half8*)&Als[wm * 32 + mt * 16 + l15][swz];
      }
      #pragma unroll
      for (int nt = 0; nt < 4; nt++) {
        bh_[nt] = *(const half8*)&Bhs[wn * 64 + nt * 16 + l15][swz];
        if (three) bl[nt] = *(const half8*)&Bls[wn * 64 + nt * 16 + l15][swz];
      }
      if (three) {
        #pragma unroll
        for (int mt = 0; mt < 2; mt++)
          #pragma unroll
          for (int nt = 0; nt < 4; nt++) {
            floatx4 t0 = MFMA_F16(ah[mt], bh_[nt], acc[mt][nt]);
            t0 = MFMA_F16(ah[mt], bl[nt], t0);
            acc[mt][nt] = MFMA_F16(al[mt], bh_[nt], t0);
          }
      } else {
        #pragma unroll
        for (int mt = 0; mt < 2; mt++)
          #pragma unroll
          for (int nt = 0; nt < 4; nt++)
            acc[mt][nt] = MFMA_F16(ah[mt], bh_[nt], acc[mt][nt]);
      }
    }
  }

  #pragma unroll
  for (int mt = 0; mt < 2; mt++)
    #pragma unroll
    for (int nt = 0; nt < 4; nt++)
      #pragma unroll
      for (int r = 0; r < 4; r++) {
        int gm = bm * 64 + wm * 32 + mt * 16 + quad * 4 + r;    // (b,s)
        int gn = bn * 128 + wn * 64 + nt * 16 + l15;            // h*64+d
        int b = gm >> 11, s = gm & 2047;
        int h = gn >> 6, d = gn & 63;
        size_t idx = ((size_t)(b * NH + h) * SEQ + s) * HD + d;
        float val = acc[mt][nt][r] * scale;
        _Float16 hi = (_Float16)val;
        yh[idx] = hi;
        if (three) yl[idx] = (_Float16)(val - (float)hi);
      }
}

// ---------------- vh [b,h,s,64] -> vhT [b,h,64,perm(s)] ----------------
// perm within 32-group: s = 32c+16a+4q+b -> pos = 32c+8q+4a+b, so flash PV
// A-fragments (key order 32kc+16(j>>2)+4quad+(j&3)) are contiguous b128 reads.
__global__ __launch_bounds__(256) void transpose_v(const _Float16* __restrict__ vh,
                                                   _Float16* __restrict__ vhT)
{
  __shared__ __align__(16) _Float16 T[128][72];
  const int bh = blockIdx.x, sc = blockIdx.y, tid = threadIdx.x;
  const _Float16* src = vh + ((size_t)bh * SEQ + sc * 128) * HD;
  #pragma unroll
  for (int i = 0; i < 4; i++) {
    int c = i * 256 + tid, row = c >> 3, off = (c & 7) * 8;
    *(half8*)&T[row][off] = *(const half8*)(src + (size_t)row * HD + off);
  }
  __syncthreads();
  _Float16* dst = vhT + (size_t)bh * HD * SEQ + sc * 128;
  #pragma unroll
  for (int i = 0; i < 4; i++) {
    int c = i * 256 + tid, hd = c >> 4, off = (c & 15) * 8;
    int base32 = off & ~31, qsel = (off >> 3) & 3;
    half8 vv;
    #pragma unroll
    for (int j = 0; j < 8; j++) {
      int s_local = base32 + 16 * (j >> 2) + 4 * qsel + (j & 3);
      vv[j] = T[s_local][hd];
    }
    *(half8*)(dst + (size_t)hd * SEQ + off) = vv;
  }
}

// ---------------- flash attention v8: XCD pin + split-K x2 + T14 async stage -
// 1-D grid 1024; bh = (id&7) + 8*((id>>3)&3) pins each bh's K/V to one XCD L2.
// 4 waves, 32 q/wave; per kt: prefetch next K/V tile into regs right after the
// top barrier, compute kt from LDS, then after the read barrier ds_write the
// regs (same XOR image). L2 latency hides under QK^T+softmax+PV.
__global__ __launch_bounds__(256, 4) void flash_kernel(
    const _Float16* __restrict__ qh_hi, const _Float16* __restrict__ qh_lo,
    const _Float16* __restrict__ kh_hi, const _Float16* __restrict__ kh_lo,
    const _Float16* __restrict__ vhT, float* __restrict__ Op, float2* __restrict__ ml)
{
  __shared__ __align__(16) _Float16 Kh[64][64];
  __shared__ __align__(16) _Float16 Kl[64][64];
  __shared__ __align__(16) _Float16 Vt[64][64];   // [d][permuted key]

  const int id = blockIdx.x;
  const int seq_ = id >> 3;
  const int bh = (id & 7) + 8 * (seq_ & 3);       // 0..31, pinned to XCD id&7
  const int rem = seq_ >> 2;
  const int qb = rem & 15;                        // 0..15
  const int kh = rem >> 4;                        // 0..1
  const int tid = threadIdx.x;
  const int wq = tid >> 6;
  const int lane = tid & 63, l15 = lane & 15, quad = lane >> 4;

  const size_t bh_off = (size_t)bh * SEQ * HD;
  const _Float16* __restrict__ kh_p = kh_hi + bh_off;
  const _Float16* __restrict__ kl_p = kh_lo + bh_off;
  const _Float16* __restrict__ vt_p = vhT + (size_t)bh * HD * SEQ;
  const int qrow0 = qb * 128 + wq * 32;

  // Q as B-operand fragments: lane holds n=q=l15, k=d=kc*32+quad*8+j
  half8 bqh[2][2], bql[2][2];         // [g][kc]
  #pragma unroll
  for (int g = 0; g < 2; g++) {
    const _Float16* qp_h = qh_hi + bh_off + (size_t)(qrow0 + g * 16 + l15) * HD;
    const _Float16* qp_l = qh_lo + bh_off + (size_t)(qrow0 + g * 16 + l15) * HD;
    #pragma unroll
    for (int kc = 0; kc < 2; kc++) {
      bqh[g][kc] = *(const half8*)(qp_h + kc * 32 + quad * 8);
      bql[g][kc] = *(const half8*)(qp_l + kc * 32 + quad * 8);
    }
  }

  // staging: wave wq covers groups 2wq, 2wq+1 per array (8 rows x 1 KiB each)
  const int r8 = lane >> 3;
  const int cp8 = ((lane & 7) ^ r8) * 8;

  float m_[2] = {-3.0e38f, -3.0e38f};
  float l_[2] = {0.f, 0.f};
  floatx4 Oacc[2][4];
  #pragma unroll
  for (int g = 0; g < 2; g++)
    #pragma unroll
    for (int nd = 0; nd < 4; nd++) Oacc[g][nd] = (floatx4){0.f, 0.f, 0.f, 0.f};

  const int kt0 = kh * 16;
  // prologue: stage tile kt0 via global_load_lds
  {
    const int kbase = kt0 * 64;
    #pragma unroll
    for (int i = 0; i < 2; i++) {
      const int g = wq * 2 + i;
      const int r = g * 8 + r8;
      gl2lds16(kh_p + (size_t)(kbase + r) * HD + cp8, &Kh[0][0] + g * 512);
      gl2lds16(kl_p + (size_t)(kbase + r) * HD + cp8, &Kl[0][0] + g * 512);
      gl2lds16(vt_p + (size_t)r * SEQ + kbase + cp8, &Vt[0][0] + g * 512);
    }
  }

  for (int kt = kt0; kt < kt0 + 16; kt++) {
    __syncthreads();                            // LDS tile kt visible

    // T14: prefetch tile kt+1 into regs; latency hides under compute below
    const bool hasnext = (kt + 1 < kt0 + 16);
    half8 rkh[2], rkl[2], rvt[2];
    if (hasnext) {
      const int kb2 = (kt + 1) * 64;
      #pragma unroll
      for (int i = 0; i < 2; i++) {
        const int g = wq * 2 + i;
        const int r = g * 8 + r8;
        rkh[i] = *(const half8*)(kh_p + (size_t)(kb2 + r) * HD + cp8);
        rkl[i] = *(const half8*)(kl_p + (size_t)(kb2 + r) * HD + cp8);
        rvt[i] = *(const half8*)(vt_p + (size_t)r * SEQ + kb2 + cp8);
      }
    }

    // S^T = K·Q^T (3-term split fp16), both q-groups share K fragments
    floatx4 sacc[2][4];
    #pragma unroll
    for (int nt = 0; nt < 4; nt++) {
      const int r7 = l15 & 7;
      half8 akh0 = *(const half8*)&Kh[nt * 16 + l15][((0 * 4 + quad) ^ r7) * 8];
      half8 akh1 = *(const half8*)&Kh[nt * 16 + l15][((1 * 4 + quad) ^ r7) * 8];
      half8 akl0 = *(const half8*)&Kl[nt * 16 + l15][((0 * 4 + quad) ^ r7) * 8];
      half8 akl1 = *(const half8*)&Kl[nt * 16 + l15][((1 * 4 + quad) ^ r7) * 8];
      #pragma unroll
      for (int g = 0; g < 2; g++) {
        floatx4 s4 = (floatx4){0.f, 0.f, 0.f, 0.f};
        s4 = MFMA_F16(akh0, bqh[g][0], s4);
        s4 = MFMA_F16(akh1, bqh[g][1], s4);
        s4 = MFMA_F16(akh0, bql[g][0], s4);
        s4 = MFMA_F16(akh1, bql[g][1], s4);
        s4 = MFMA_F16(akl0, bqh[g][0], s4);
        s4 = MFMA_F16(akl1, bqh[g][1], s4);
        sacc[g][nt] = s4;
      }
    }

    // V A-fragments (permuted image), shared by both q-groups
    half8 av[4][2];
    {
      const int r7 = l15 & 7;
      #pragma unroll
      for (int nd = 0; nd < 4; nd++) {
        av[nd][0] = *(const half8*)&Vt[nd * 16 + l15][((0 * 4 + quad) ^ r7) * 8];
        av[nd][1] = *(const half8*)&Vt[nd * 16 + l15][((1 * 4 + quad) ^ r7) * 8];
      }
    }

    #pragma unroll
    for (int g = 0; g < 2; g++) {
      // online softmax over 64 keys: in-lane + 2 cross-quad shuffles
      float rmax = sacc[g][0][0];
      #pragma unroll
      for (int nt = 0; nt < 4; nt++)
        #pragma unroll
        for (int r = 0; r < 4; r++) rmax = fmaxf(rmax, sacc[g][nt][r]);
      rmax = fmaxf(rmax, __shfl_xor(rmax, 16, 64));
      rmax = fmaxf(rmax, __shfl_xor(rmax, 32, 64));
      const float mnew = fmaxf(m_[g], rmax);
      const float alpha = exp2f(m_[g] - mnew);
      m_[g] = mnew;

      float rsum = 0.f;
      #pragma unroll
      for (int nt = 0; nt < 4; nt++)
        #pragma unroll
        for (int r = 0; r < 4; r++) {
          float p = exp2f(sacc[g][nt][r] - mnew);
          sacc[g][nt][r] = p;
          rsum += p;
        }
      rsum += __shfl_xor(rsum, 16, 64);
      rsum += __shfl_xor(rsum, 32, 64);
      l_[g] = l_[g] * alpha + rsum;

      // P pack for PV B-operand: bp8[kc][j] = p[2kc + (j>>2)][j&3] (in-lane)
      half8 bp8[2];
      #pragma unroll
      for (int kc = 0; kc < 2; kc++)
        #pragma unroll
        for (int j = 0; j < 8; j++)
          bp8[kc][j] = (_Float16)sacc[g][2 * kc + (j >> 2)][j & 3];

      #pragma unroll
      for (int nd = 0; nd < 4; nd++) {
        Oacc[g][nd][0] *= alpha; Oacc[g][nd][1] *= alpha;
        Oacc[g][nd][2] *= alpha; Oacc[g][nd][3] *= alpha;
        Oacc[g][nd] = MFMA_F16(av[nd][0], bp8[0], Oacc[g][nd]);
        Oacc[g][nd] = MFMA_F16(av[nd][1], bp8[1], Oacc[g][nd]);
      }
    }

    __syncthreads();                            // all waves done reading kt
    if (hasnext) {
      #pragma unroll
      for (int i = 0; i < 2; i++) {
        const int g = wq * 2 + i;
        *(half8*)(&Kh[0][0] + g * 512 + lane * 8) = rkh[i];
        *(half8*)(&Kl[0][0] + g * 512 + lane * 8) = rkl[i];
        *(half8*)(&Vt[0][0] + g * 512 + lane * 8) = rvt[i];
      }
    }
  }

  // epilogue: unnormalized O^T partial + (m,l)
  const size_t fqbase = (size_t)bh * SEQ + qrow0;
  #pragma unroll
  for (int g = 0; g < 2; g++) {
    const size_t fq = fqbase + g * 16 + l15;
    float* ob = Op + ((size_t)kh * 65536 + fq) * HD;
    #pragma unroll
    for (int nd = 0; nd < 4; nd++) {
      float4 vv;
      vv.x = Oacc[g][nd][0]; vv.y = Oacc[g][nd][1];
      vv.z = Oacc[g][nd][2]; vv.w = Oacc[g][nd][3];
      *(float4*)(ob + nd * 16 + quad * 4) = vv;
    }
    if (quad == 0) ml[kh * 65536 + fq] = make_float2(m_[g], l_[g]);
  }
}

// ---------------- merge the two split-K partials ----------------
__global__ __launch_bounds__(256) void merge_kernel(const float* __restrict__ Op,
                                                    const float2* __restrict__ ml,
                                                    float* __restrict__ out)
{
  const int tid = threadIdx.x;
  const int fq = blockIdx.x * 64 + (tid >> 2);
  const int dp = (tid & 3) * 16;
  float2 m0 = ml[fq], m1 = ml[65536 + fq];
  float M = fmaxf(m0.x, m1.x);
  float w0 = exp2f(m0.x - M), w1 = exp2f(m1.x - M);
  float rinv = 1.0f / (m0.y * w0 + m1.y * w1);
  int bh = fq >> 11, s = fq & 2047, b = bh >> 4, h = bh & 15;
  float* ob = out + ((size_t)(b * SEQ + s)) * DM + h * HD + dp;
  const float* p0 = Op + (size_t)fq * HD + dp;
  const float* p1 = p0 + (size_t)65536 * HD;
  #pragma unroll
  for (int j = 0; j < 4; j++) {
    float4 a = *(const float4*)(p0 + 4 * j);
    float4 c = *(const float4*)(p1 + 4 * j);
    float4 r;
    r.x = (a.x * w0 + c.x * w1) * rinv;
    r.y = (a.y * w0 + c.y * w1) * rinv;
    r.z = (a.z * w0 + c.z * w1) * rinv;
    r.w = (a.w * w0 + c.w * w1) * rinv;
    *(float4*)(ob + 4 * j) = r;
  }
}

extern "C" void kernel_launch(void* const* d_in, const int* in_sizes, int n_in,
                              void* d_out, int out_size, void* d_ws, size_t ws_size,
                              hipStream_t stream) {
  const float* q  = (const float*)d_in[0];
  const float* k  = (const float*)d_in[1];
  const float* v  = (const float*)d_in[2];
  const float* Wq = (const float*)d_in[3];
  const float* Wk = (const float*)d_in[4];
  const float* Wv = (const float*)d_in[5];
  float* out = (float*)d_out;

  char* W = (char*)d_ws;
  const size_t MiB = 1ull << 20;
  _Float16* qh_hi = (_Float16*)(W + 0 * MiB);
  _Float16* qh_lo = (_Float16*)(W + 8 * MiB);
  _Float16* kh_hi = (_Float16*)(W + 16 * MiB);
  _Float16* kh_lo = (_Float16*)(W + 24 * MiB);
  _Float16* vhT   = (_Float16*)(W + 32 * MiB);
  _Float16* vh    = (_Float16*)(W + 40 * MiB);  // dead after transpose_v
  _Float16* xh    = (_Float16*)(W + 48 * MiB);  // dead after last proj
  _Float16* xl    = (_Float16*)(W + 56 * MiB);
  _Float16* Wh    = (_Float16*)(W + 64 * MiB);
  _Float16* Wl    = (_Float16*)(W + 66 * MiB);
  float*    Op    = (float*)  (W + 40 * MiB);   // 2 x 16 MiB, aliases vh/xh/xl/Wh/Wl
  float2*   mlp   = (float2*) (W + 72 * MiB);   // 1 MiB; total 73 MiB

  // Q
  convert_kernel<<<5120, 256, 0, stream>>>(q, Wq, xh, xl, Wh, Wl, 1);
  proj_kernel<<<dim3(64, 8), 256, 0, stream>>>(xh, xl, Wh, Wl, qh_hi, qh_lo, QSCALE, 1);
  // K
  convert_kernel<<<5120, 256, 0, stream>>>(k, Wk, xh, xl, Wh, Wl, 1);
  proj_kernel<<<dim3(64, 8), 256, 0, stream>>>(xh, xl, Wh, Wl, kh_hi, kh_lo, 1.0f, 1);
  // V (single-term)
  convert_kernel<<<5120, 256, 0, stream>>>(v, Wv, xh, xl, Wh, Wl, 0);
  proj_kernel<<<dim3(64, 8), 256, 0, stream>>>(xh, xl, Wh, Wl, vh, vh, 1.0f, 0);

  transpose_v<<<dim3(32, 16), 256, 0, stream>>>(vh, vhT);
  flash_kernel<<<1024, 256, 0, stream>>>(qh_hi, qh_lo, kh_hi, kh_lo, vhT, Op, mlp);
  merge_kernel<<<1024, 256, 0, stream>>>(Op, mlp, out);
}

// Round 2
// 382.301 us; speedup vs baseline: 1.3566x; 1.3566x over previous
//
#include <hip/hip_runtime.h>

// MultiHeadAttention: B=2, S=2048, D=1024, H=16, HD=64, scores MULTIPLIED by 64.
// Round 9: proj reverted to R7 128x128 (R8 re-tile was neutral). flash:
// reverted T14 reg-prefetch (R8 post-mortem: scratch spill, WRITE_SIZE 938 MB),
// instead raise parallelism structurally: split-K x4 (grid 2048 -> 8 blocks/CU,
// was grid-limited at 4) and drop V LDS staging (V is 256 KB/bh, XCD-pinned
// L2-resident; PV fragments are contiguous 16B global reads via the vhT perm).
// LDS 16 KiB, VGPR pressure unchanged. KSPLIT=2 fallback if ws_size < 106 MiB.
// LDS image: row r, logical chunk c stored at col (c ^ (r&7)) -- 2-way banks (free).
// Workspace (KSPLIT=4): 0 qh_hi | 8 qh_lo | 16 kh_hi | 24 kh_lo | 32 vhT | 40 vh
//   | 48 xh | 56 xl | 64 Wh | 66 Wl ; Op 40..104 (aliases vh/xh/xl/Wh/Wl) ;
//   ml 104..106. Total 106 MiB.

typedef _Float16 half4 __attribute__((ext_vector_type(4)));
typedef _Float16 half8 __attribute__((ext_vector_type(8)));
typedef float floatx4 __attribute__((ext_vector_type(4)));

#define MFMA_F16(a, b, c) __builtin_amdgcn_mfma_f32_16x16x32_f16((a), (b), (c), 0, 0, 0)

constexpr int SEQ = 2048;
constexpr int DM = 1024;
constexpr int NH = 16;
constexpr int HD = 64;
// 64 * log2(e): fold score scale + base-2 conversion into Q projection
constexpr float QSCALE = 92.33248261689366f;

// async 16B/lane global->LDS copy; LDS dest = wave-uniform base + lane*16
__device__ __forceinline__ void gl2lds16(const _Float16* g, _Float16* l) {
  __builtin_amdgcn_global_load_lds(
      (const __attribute__((address_space(1))) void*)g,
      (__attribute__((address_space(3))) void*)l, 16, 0, 0);
}

__device__ inline void split4(const float4 f, half4& h, half4& l) {
  h[0] = (_Float16)f.x; l[0] = (_Float16)(f.x - (float)h[0]);
  h[1] = (_Float16)f.y; l[1] = (_Float16)(f.y - (float)h[1]);
  h[2] = (_Float16)f.z; l[2] = (_Float16)(f.z - (float)h[2]);
  h[3] = (_Float16)f.w; l[3] = (_Float16)(f.w - (float)h[3]);
}

// ---------------- convert: fp32 -> fp16 hi (+lo) ----------------
// blocks 0..4095: x (4M floats); blocks 4096..5119: W (1M floats)
__global__ __launch_bounds__(256) void convert_kernel(
    const float* __restrict__ x, const float* __restrict__ W,
    _Float16* __restrict__ xh, _Float16* __restrict__ xl,
    _Float16* __restrict__ Wh, _Float16* __restrict__ Wl, int do_lo)
{
  if (blockIdx.x < 4096) {
    int idx = blockIdx.x * 256 + threadIdx.x;
    float4 f = ((const float4*)x)[idx];
    half4 h, l; split4(f, h, l);
    *(half4*)(xh + (size_t)idx * 4) = h;
    if (do_lo) *(half4*)(xl + (size_t)idx * 4) = l;
  } else {
    int idx = (blockIdx.x - 4096) * 256 + threadIdx.x;
    float4 f = ((const float4*)W)[idx];
    half4 h, l; split4(f, h, l);
    *(half4*)(Wh + (size_t)idx * 4) = h;
    if (do_lo) *(half4*)(Wl + (size_t)idx * 4) = l;
  }
}

// ---------------- projection GEMM: y = A @ B^T (pre-converted fp16) ---------
// 128x128 tile, BK=64, global_load_lds staging (m97-style 2-barrier loop).
// three=1: 3-term split-fp16, writes yh+yl; three=0: single-term, yh only.
__global__ __launch_bounds__(256, 1) void proj_kernel(
    const _Float16* __restrict__ Ahg, const _Float16* __restrict__ Alg,
    const _Float16* __restrict__ Bhg, const _Float16* __restrict__ Blg,
    _Float16* __restrict__ yh, _Float16* __restrict__ yl,
    float scale, int three)
{
  __shared__ __align__(16) _Float16 Ahs[128][64];
  __shared__ __align__(16) _Float16 Als[128][64];
  __shared__ __align__(16) _Float16 Bhs[128][64];
  __shared__ __align__(16) _Float16 Bls[128][64];

  const int tid = threadIdx.x;
  const int bm = blockIdx.x;          // 0..31
  const int bn = blockIdx.y;          // 0..7
  const int lane = tid & 63, l15 = lane & 15, quad = lane >> 4;
  const int w = tid >> 6, wm = w >> 1, wn = w & 1;

  // staging: wave w stages groups g = 4w+i (8 rows x 1 KiB each) of each array.
  // lane L: row-in-group = L>>3, fetches logical chunk (L&7)^(L>>3) -> XOR image.
  const int r8 = lane >> 3;
  const int cp8 = (((lane & 7) ^ r8)) * 8;    // half offset within row
  int grow[4]; _Float16* la[4]; _Float16* lal[4]; _Float16* lb[4]; _Float16* lbl[4];
  #pragma unroll
  for (int i = 0; i < 4; i++) {
    const int g = w * 4 + i;
    grow[i] = g * 8 + r8;                     // row 0..127 (per-lane)
    la[i]  = &Ahs[0][0] + g * 512;            // wave-uniform LDS bases
    lal[i] = &Als[0][0] + g * 512;
    lb[i]  = &Bhs[0][0] + g * 512;
    lbl[i] = &Bls[0][0] + g * 512;
  }

  floatx4 acc[4][4];
  #pragma unroll
  for (int mt = 0; mt < 4; mt++)
    #pragma unroll
    for (int nt = 0; nt < 4; nt++)
      acc[mt][nt] = (floatx4){0.f, 0.f, 0.f, 0.f};

  for (int kk = 0; kk < DM; kk += 64) {
    __syncthreads();                          // prior tile's reads complete
    #pragma unroll
    for (int i = 0; i < 4; i++) {
      const size_t ga = (size_t)(bm * 128 + grow[i]) * DM + kk + cp8;
      const size_t gb = (size_t)(bn * 128 + grow[i]) * DM + kk + cp8;
      gl2lds16(Ahg + ga, la[i]);
      gl2lds16(Bhg + gb, lb[i]);
      if (three) {
        gl2lds16(Alg + ga, lal[i]);
        gl2lds16(Blg + gb, lbl[i]);
      }
    }
    __syncthreads();                          // vmcnt(0) drain: tile visible

    #pragma unroll
    for (int kc = 0; kc < 2; kc++) {
      const int swz = ((kc * 4 + quad) ^ (l15 & 7)) * 8;
      half8 ah[4], bh_[4], al[4], bl[4];
      #pragma unroll
      for (int t = 0; t < 4; t++) {
        ah[t]  = *(const half8*)&Ahs[wm * 64 + t * 16 + l15][swz];
        bh_[t] = *(const half8*)&Bhs[wn * 64 + t * 16 + l15][swz];
        if (three) {
          al[t] = *(const half8*)&Als[wm * 64 + t * 16 + l15][swz];
          bl[t] = *(const half8*)&Bls[wn * 64 + t * 16 + l15][swz];
        }
      }
      if (three) {
        #pragma unroll
        for (int mt = 0; mt < 4; mt++)
          #pragma unroll
          for (int nt = 0; nt < 4; nt++) {
            floatx4 t0 = MFMA_F16(ah[mt], bh_[nt], acc[mt][nt]);
            t0 = MFMA_F16(ah[mt], bl[nt], t0);
            acc[mt][nt] = MFMA_F16(al[mt], bh_[nt], t0);
          }
      } else {
        #pragma unroll
        for (int mt = 0; mt < 4; mt++)
          #pragma unroll
          for (int nt = 0; nt < 4; nt++)
            acc[mt][nt] = MFMA_F16(ah[mt], bh_[nt], acc[mt][nt]);
      }
    }
  }

  #pragma unroll
  for (int mt = 0; mt < 4; mt++)
    #pragma unroll
    for (int nt = 0; nt < 4; nt++)
      #pragma unroll
      for (int r = 0; r < 4; r++) {
        int gm = bm * 128 + wm * 64 + mt * 16 + quad * 4 + r;   // (b,s)
        int gn = bn * 128 + wn * 64 + nt * 16 + l15;            // h*64+d
        int b = gm >> 11, s = gm & 2047;
        int h = gn >> 6, d = gn & 63;
        size_t idx = ((size_t)(b * NH + h) * SEQ + s) * HD + d;
        float val = acc[mt][nt][r] * scale;
        _Float16 hi = (_Float16)val;
        yh[idx] = hi;
        if (three) yl[idx] = (_Float16)(val - (float)hi);
      }
}

// ---------------- vh [b,h,s,64] -> vhT [b,h,64,perm(s)] ----------------
// perm within 32-group: s = 32c+16a+4q+b -> pos = 32c+8q+4a+b, so flash PV
// A-fragments (key order 32kc+16(j>>2)+4quad+(j&3)) are contiguous b128 reads.
__global__ __launch_bounds__(256) void transpose_v(const _Float16* __restrict__ vh,
                                                   _Float16* __restrict__ vhT)
{
  __shared__ __align__(16) _Float16 T[128][72];
  const int bh = blockIdx.x, sc = blockIdx.y, tid = threadIdx.x;
  const _Float16* src = vh + ((size_t)bh * SEQ + sc * 128) * HD;
  #pragma unroll
  for (int i = 0; i < 4; i++) {
    int c = i * 256 + tid, row = c >> 3, off = (c & 7) * 8;
    *(half8*)&T[row][off] = *(const half8*)(src + (size_t)row * HD + off);
  }
  __syncthreads();
  _Float16* dst = vhT + (size_t)bh * HD * SEQ + sc * 128;
  #pragma unroll
  for (int i = 0; i < 4; i++) {
    int c = i * 256 + tid, hd = c >> 4, off = (c & 15) * 8;
    int base32 = off & ~31, qsel = (off >> 3) & 3;
    half8 vv;
    #pragma unroll
    for (int j = 0; j < 8; j++) {
      int s_local = base32 + 16 * (j >> 2) + 4 * qsel + (j & 3);
      vv[j] = T[s_local][hd];
    }
    *(half8*)(dst + (size_t)hd * SEQ + off) = vv;
  }
}

// ---------------- flash attention v9: XCD pin + split-K xKSPLIT + V direct --
// grid 512*KSPLIT; bh = (id&7) + 8*((id>>3)&3) pins each bh's K/V to one XCD L2.
// 4 waves, 32 q/wave; K hi/lo staged via global_load_lds (XOR image, 16 KiB LDS);
// V fragments read directly from vhT (L2-resident, contiguous 16B via perm).
// KSPLIT=4 -> 2048 blocks = 8 blocks/CU (grid was the occupancy limiter at 4).
template<int KSPLIT>
__global__ __launch_bounds__(256, 4) void flash_kernel(
    const _Float16* __restrict__ qh_hi, const _Float16* __restrict__ qh_lo,
    const _Float16* __restrict__ kh_hi, const _Float16* __restrict__ kh_lo,
    const _Float16* __restrict__ vhT, float* __restrict__ Op, float2* __restrict__ ml)
{
  __shared__ __align__(16) _Float16 Kh[64][64];
  __shared__ __align__(16) _Float16 Kl[64][64];

  constexpr int NKT = 32 / KSPLIT;                // K-tiles per block
  const int id = blockIdx.x;
  const int bh = (id & 7) + 8 * ((id >> 3) & 3);  // 0..31, pinned to XCD id&7
  const int rem = id >> 5;
  const int qb = rem & 15;                        // 0..15
  const int kh = rem >> 4;                        // 0..KSPLIT-1
  const int tid = threadIdx.x;
  const int wq = tid >> 6;
  const int lane = tid & 63, l15 = lane & 15, quad = lane >> 4;

  const size_t bh_off = (size_t)bh * SEQ * HD;
  const _Float16* __restrict__ kh_p = kh_hi + bh_off;
  const _Float16* __restrict__ kl_p = kh_lo + bh_off;
  const _Float16* __restrict__ vt_p = vhT + (size_t)bh * HD * SEQ;
  const int qrow0 = qb * 128 + wq * 32;

  // Q as B-operand fragments: lane holds n=q=l15, k=d=kc*32+quad*8+j
  half8 bqh[2][2], bql[2][2];         // [g][kc]
  #pragma unroll
  for (int g = 0; g < 2; g++) {
    const _Float16* qp_h = qh_hi + bh_off + (size_t)(qrow0 + g * 16 + l15) * HD;
    const _Float16* qp_l = qh_lo + bh_off + (size_t)(qrow0 + g * 16 + l15) * HD;
    #pragma unroll
    for (int kc = 0; kc < 2; kc++) {
      bqh[g][kc] = *(const half8*)(qp_h + kc * 32 + quad * 8);
      bql[g][kc] = *(const half8*)(qp_l + kc * 32 + quad * 8);
    }
  }

  // staging: wave wq covers groups 2wq, 2wq+1 per array (8 rows x 1 KiB each)
  const int r8 = lane >> 3;
  const int cp8 = ((lane & 7) ^ r8) * 8;

  float m_[2] = {-3.0e38f, -3.0e38f};
  float l_[2] = {0.f, 0.f};
  floatx4 Oacc[2][4];
  #pragma unroll
  for (int g = 0; g < 2; g++)
    #pragma unroll
    for (int nd = 0; nd < 4; nd++) Oacc[g][nd] = (floatx4){0.f, 0.f, 0.f, 0.f};

  const int kt0 = kh * NKT;
  for (int kt = kt0; kt < kt0 + NKT; kt++) {
    const int kbase = kt * 64;
    __syncthreads();                            // prior tile's LDS reads done
    #pragma unroll
    for (int i = 0; i < 2; i++) {
      const int g = wq * 2 + i;
      const int r = g * 8 + r8;
      gl2lds16(kh_p + (size_t)(kbase + r) * HD + cp8, &Kh[0][0] + g * 512);
      gl2lds16(kl_p + (size_t)(kbase + r) * HD + cp8, &Kl[0][0] + g * 512);
    }
    __syncthreads();                            // vmcnt(0) drain: K tile visible

    // S^T = K·Q^T (3-term split fp16), both q-groups share K fragments
    floatx4 sacc[2][4];
    #pragma unroll
    for (int nt = 0; nt < 4; nt++) {
      const int r7 = l15 & 7;
      half8 akh0 = *(const half8*)&Kh[nt * 16 + l15][((0 * 4 + quad) ^ r7) * 8];
      half8 akh1 = *(const half8*)&Kh[nt * 16 + l15][((1 * 4 + quad) ^ r7) * 8];
      half8 akl0 = *(const half8*)&Kl[nt * 16 + l15][((0 * 4 + quad) ^ r7) * 8];
      half8 akl1 = *(const half8*)&Kl[nt * 16 + l15][((1 * 4 + quad) ^ r7) * 8];
      #pragma unroll
      for (int g = 0; g < 2; g++) {
        floatx4 s4 = (floatx4){0.f, 0.f, 0.f, 0.f};
        s4 = MFMA_F16(akh0, bqh[g][0], s4);
        s4 = MFMA_F16(akh1, bqh[g][1], s4);
        s4 = MFMA_F16(akh0, bql[g][0], s4);
        s4 = MFMA_F16(akh1, bql[g][1], s4);
        s4 = MFMA_F16(akl0, bqh[g][0], s4);
        s4 = MFMA_F16(akl1, bqh[g][1], s4);
        sacc[g][nt] = s4;
      }
    }

    // V A-fragments direct from global (L2-resident, contiguous 16B via perm);
    // issued here so L2 latency hides under g=0 softmax VALU.
    half8 av[4][2];
    #pragma unroll
    for (int nd = 0; nd < 4; nd++) {
      const _Float16* vp = vt_p + (size_t)(nd * 16 + l15) * SEQ + kbase;
      av[nd][0] = *(const half8*)(vp + quad * 8);
      av[nd][1] = *(const half8*)(vp + 32 + quad * 8);
    }

    #pragma unroll
    for (int g = 0; g < 2; g++) {
      // online softmax over 64 keys: in-lane + 2 cross-quad shuffles
      float rmax = sacc[g][0][0];
      #pragma unroll
      for (int nt = 0; nt < 4; nt++)
        #pragma unroll
        for (int r = 0; r < 4; r++) rmax = fmaxf(rmax, sacc[g][nt][r]);
      rmax = fmaxf(rmax, __shfl_xor(rmax, 16, 64));
      rmax = fmaxf(rmax, __shfl_xor(rmax, 32, 64));
      const float mnew = fmaxf(m_[g], rmax);
      const float alpha = exp2f(m_[g] - mnew);
      m_[g] = mnew;

      float rsum = 0.f;
      #pragma unroll
      for (int nt = 0; nt < 4; nt++)
        #pragma unroll
        for (int r = 0; r < 4; r++) {
          float p = exp2f(sacc[g][nt][r] - mnew);
          sacc[g][nt][r] = p;
          rsum += p;
        }
      rsum += __shfl_xor(rsum, 16, 64);
      rsum += __shfl_xor(rsum, 32, 64);
      l_[g] = l_[g] * alpha + rsum;

      // P pack for PV B-operand: bp8[kc][j] = p[2kc + (j>>2)][j&3] (in-lane)
      half8 bp8[2];
      #pragma unroll
      for (int kc = 0; kc < 2; kc++)
        #pragma unroll
        for (int j = 0; j < 8; j++)
          bp8[kc][j] = (_Float16)sacc[g][2 * kc + (j >> 2)][j & 3];

      #pragma unroll
      for (int nd = 0; nd < 4; nd++) {
        Oacc[g][nd][0] *= alpha; Oacc[g][nd][1] *= alpha;
        Oacc[g][nd][2] *= alpha; Oacc[g][nd][3] *= alpha;
        Oacc[g][nd] = MFMA_F16(av[nd][0], bp8[0], Oacc[g][nd]);
        Oacc[g][nd] = MFMA_F16(av[nd][1], bp8[1], Oacc[g][nd]);
      }
    }
  }

  // epilogue: unnormalized O^T partial + (m,l)
  const size_t fqbase = (size_t)bh * SEQ + qrow0;
  #pragma unroll
  for (int g = 0; g < 2; g++) {
    const size_t fq = fqbase + g * 16 + l15;
    float* ob = Op + ((size_t)kh * 65536 + fq) * HD;
    #pragma unroll
    for (int nd = 0; nd < 4; nd++) {
      float4 vv;
      vv.x = Oacc[g][nd][0]; vv.y = Oacc[g][nd][1];
      vv.z = Oacc[g][nd][2]; vv.w = Oacc[g][nd][3];
      *(float4*)(ob + nd * 16 + quad * 4) = vv;
    }
    if (quad == 0) ml[kh * 65536 + fq] = make_float2(m_[g], l_[g]);
  }
}

// ---------------- merge the KSPLIT split-K partials ----------------
template<int KSPLIT>
__global__ __launch_bounds__(256) void merge_kernel(const float* __restrict__ Op,
                                                    const float2* __restrict__ ml,
                                                    float* __restrict__ out)
{
  const int tid = threadIdx.x;
  const int fq = blockIdx.x * 64 + (tid >> 2);
  const int dp = (tid & 3) * 16;
  float2 mls[KSPLIT];
  float M = -3.0e38f;
  #pragma unroll
  for (int s = 0; s < KSPLIT; s++) {
    mls[s] = ml[s * 65536 + fq];
    M = fmaxf(M, mls[s].x);
  }
  float wsum = 0.f, w[KSPLIT];
  #pragma unroll
  for (int s = 0; s < KSPLIT; s++) {
    w[s] = exp2f(mls[s].x - M);
    wsum += mls[s].y * w[s];
  }
  const float rinv = 1.0f / wsum;
  int bh = fq >> 11, sq = fq & 2047, b = bh >> 4, h = bh & 15;
  float* ob = out + ((size_t)(b * SEQ + sq)) * DM + h * HD + dp;
  const float* p0 = Op + (size_t)fq * HD + dp;
  #pragma unroll
  for (int j = 0; j < 4; j++) {
    float4 r = make_float4(0.f, 0.f, 0.f, 0.f);
    #pragma unroll
    for (int s = 0; s < KSPLIT; s++) {
      float4 a = *(const float4*)(p0 + (size_t)s * 65536 * HD + 4 * j);
      r.x += a.x * w[s]; r.y += a.y * w[s];
      r.z += a.z * w[s]; r.w += a.w * w[s];
    }
    r.x *= rinv; r.y *= rinv; r.z *= rinv; r.w *= rinv;
    *(float4*)(ob + 4 * j) = r;
  }
}

extern "C" void kernel_launch(void* const* d_in, const int* in_sizes, int n_in,
                              void* d_out, int out_size, void* d_ws, size_t ws_size,
                              hipStream_t stream) {
  const float* q  = (const float*)d_in[0];
  const float* k  = (const float*)d_in[1];
  const float* v  = (const float*)d_in[2];
  const float* Wq = (const float*)d_in[3];
  const float* Wk = (const float*)d_in[4];
  const float* Wv = (const float*)d_in[5];
  float* out = (float*)d_out;

  char* W = (char*)d_ws;
  const size_t MiB = 1ull << 20;
  _Float16* qh_hi = (_Float16*)(W + 0 * MiB);
  _Float16* qh_lo = (_Float16*)(W + 8 * MiB);
  _Float16* kh_hi = (_Float16*)(W + 16 * MiB);
  _Float16* kh_lo = (_Float16*)(W + 24 * MiB);
  _Float16* vhT   = (_Float16*)(W + 32 * MiB);
  _Float16* vh    = (_Float16*)(W + 40 * MiB);  // dead after transpose_v
  _Float16* xh    = (_Float16*)(W + 48 * MiB);  // dead after last proj
  _Float16* xl    = (_Float16*)(W + 56 * MiB);
  _Float16* Wh    = (_Float16*)(W + 64 * MiB);
  _Float16* Wl    = (_Float16*)(W + 66 * MiB);
  float*    Op    = (float*)  (W + 40 * MiB);   // KSPLIT x 16 MiB, aliases above

  // Q
  convert_kernel<<<5120, 256, 0, stream>>>(q, Wq, xh, xl, Wh, Wl, 1);
  proj_kernel<<<dim3(32, 8), 256, 0, stream>>>(xh, xl, Wh, Wl, qh_hi, qh_lo, QSCALE, 1);
  // K
  convert_kernel<<<5120, 256, 0, stream>>>(k, Wk, xh, xl, Wh, Wl, 1);
  proj_kernel<<<dim3(32, 8), 256, 0, stream>>>(xh, xl, Wh, Wl, kh_hi, kh_lo, 1.0f, 1);
  // V (single-term)
  convert_kernel<<<5120, 256, 0, stream>>>(v, Wv, xh, xl, Wh, Wl, 0);
  proj_kernel<<<dim3(32, 8), 256, 0, stream>>>(xh, xl, Wh, Wl, vh, vh, 1.0f, 0);

  transpose_v<<<dim3(32, 16), 256, 0, stream>>>(vh, vhT);

  if (ws_size == 0 || ws_size >= 106 * MiB) {
    // KSPLIT=4: Op 40..104, ml 104..106
    float2* mlp = (float2*)(W + 104 * MiB);
    flash_kernel<4><<<2048, 256, 0, stream>>>(qh_hi, qh_lo, kh_hi, kh_lo, vhT, Op, mlp);
    merge_kernel<4><<<1024, 256, 0, stream>>>(Op, mlp, out);
  } else {
    // KSPLIT=2 fallback: Op 40..72, ml 72..73 (R7 layout)
    float2* mlp = (float2*)(W + 72 * MiB);
    flash_kernel<2><<<1024, 256, 0, stream>>>(qh_hi, qh_lo, kh_hi, kh_lo, vhT, Op, mlp);
    merge_kernel<2><<<1024, 256, 0, stream>>>(Op, mlp, out);
  }
}

// Round 3
// 322.024 us; speedup vs baseline: 1.6106x; 1.1872x over previous
//
#include <hip/hip_runtime.h>

// MultiHeadAttention: B=2, S=2048, D=1024, H=16, HD=64, scores MULTIPLIED by 64.
// Round 10: revert to R7 grid/mapping (KSPLIT=2, V staged in LDS — R9's
// KSPLIT=4 + V-direct quadrupled FETCH). Fix the actual stall (per-iter
// immediate vmcnt(0) drain) with the T3 minimum-2-phase recipe:
//  - proj: LDS double-buffered (128 KiB, grid already 1 block/CU so free);
//    stage(t+1) issued BEFORE compute(t); one barrier per K-tile.
//  - flash: K hi/lo double-buffered + V single (40960 B -> still 4 blocks/CU);
//    V(t)+K(t+1) issued before QK^T+softmax, drained at the mid barrier, PV after.
// No reg-prefetch (R8 spill lesson), no inline asm.
// LDS image: row r, logical chunk c stored at col (c ^ (r&7)) -- 2-way banks (free).
// Workspace 73 MiB: 0 qh_hi | 8 qh_lo | 16 kh_hi | 24 kh_lo | 32 vhT | 40 vh
//   | 48 xh | 56 xl | 64 Wh | 66 Wl ; Op aliases 40..72 ; 72 ml.

typedef _Float16 half4 __attribute__((ext_vector_type(4)));
typedef _Float16 half8 __attribute__((ext_vector_type(8)));
typedef float floatx4 __attribute__((ext_vector_type(4)));

#define MFMA_F16(a, b, c) __builtin_amdgcn_mfma_f32_16x16x32_f16((a), (b), (c), 0, 0, 0)

constexpr int SEQ = 2048;
constexpr int DM = 1024;
constexpr int NH = 16;
constexpr int HD = 64;
// 64 * log2(e): fold score scale + base-2 conversion into Q projection
constexpr float QSCALE = 92.33248261689366f;

// async 16B/lane global->LDS copy; LDS dest = wave-uniform base + lane*16
__device__ __forceinline__ void gl2lds16(const _Float16* g, _Float16* l) {
  __builtin_amdgcn_global_load_lds(
      (const __attribute__((address_space(1))) void*)g,
      (__attribute__((address_space(3))) void*)l, 16, 0, 0);
}

__device__ inline void split4(const float4 f, half4& h, half4& l) {
  h[0] = (_Float16)f.x; l[0] = (_Float16)(f.x - (float)h[0]);
  h[1] = (_Float16)f.y; l[1] = (_Float16)(f.y - (float)h[1]);
  h[2] = (_Float16)f.z; l[2] = (_Float16)(f.z - (float)h[2]);
  h[3] = (_Float16)f.w; l[3] = (_Float16)(f.w - (float)h[3]);
}

// ---------------- convert: fp32 -> fp16 hi (+lo) ----------------
// blocks 0..4095: x (4M floats); blocks 4096..5119: W (1M floats)
__global__ __launch_bounds__(256) void convert_kernel(
    const float* __restrict__ x, const float* __restrict__ W,
    _Float16* __restrict__ xh, _Float16* __restrict__ xl,
    _Float16* __restrict__ Wh, _Float16* __restrict__ Wl, int do_lo)
{
  if (blockIdx.x < 4096) {
    int idx = blockIdx.x * 256 + threadIdx.x;
    float4 f = ((const float4*)x)[idx];
    half4 h, l; split4(f, h, l);
    *(half4*)(xh + (size_t)idx * 4) = h;
    if (do_lo) *(half4*)(xl + (size_t)idx * 4) = l;
  } else {
    int idx = (blockIdx.x - 4096) * 256 + threadIdx.x;
    float4 f = ((const float4*)W)[idx];
    half4 h, l; split4(f, h, l);
    *(half4*)(Wh + (size_t)idx * 4) = h;
    if (do_lo) *(half4*)(Wl + (size_t)idx * 4) = l;
  }
}

// ---------------- projection GEMM: y = A @ B^T (pre-converted fp16) ---------
// 128x128 tile, BK=64, global_load_lds staging, DOUBLE-BUFFERED (128 KiB LDS;
// grid 256 = 1 block/CU so the extra LDS is free). Per tile: one barrier,
// stage(t+1) issued before compute(t) -> loads drain a full compute phase later.
// three=1: 3-term split-fp16, writes yh+yl; three=0: single-term, yh only.
__global__ __launch_bounds__(256, 1) void proj_kernel(
    const _Float16* __restrict__ Ahg, const _Float16* __restrict__ Alg,
    const _Float16* __restrict__ Bhg, const _Float16* __restrict__ Blg,
    _Float16* __restrict__ yh, _Float16* __restrict__ yl,
    float scale, int three)
{
  __shared__ __align__(16) _Float16 Ahs[2][128][64];
  __shared__ __align__(16) _Float16 Als[2][128][64];
  __shared__ __align__(16) _Float16 Bhs[2][128][64];
  __shared__ __align__(16) _Float16 Bls[2][128][64];

  const int tid = threadIdx.x;
  const int bm = blockIdx.x;          // 0..31
  const int bn = blockIdx.y;          // 0..7
  const int lane = tid & 63, l15 = lane & 15, quad = lane >> 4;
  const int w = tid >> 6, wm = w >> 1, wn = w & 1;

  // staging: wave w stages groups g = 4w+i (8 rows x 1 KiB each) of each array.
  // lane L: row-in-group = L>>3, fetches logical chunk (L&7)^(L>>3) -> XOR image.
  const int r8 = lane >> 3;
  const int cp8 = (((lane & 7) ^ r8)) * 8;    // half offset within row
  int grow[4];
  #pragma unroll
  for (int i = 0; i < 4; i++) grow[i] = (w * 4 + i) * 8 + r8;

  floatx4 acc[4][4];
  #pragma unroll
  for (int mt = 0; mt < 4; mt++)
    #pragma unroll
    for (int nt = 0; nt < 4; nt++)
      acc[mt][nt] = (floatx4){0.f, 0.f, 0.f, 0.f};

  // prologue: stage tile 0 into buffer 0
  #pragma unroll
  for (int i = 0; i < 4; i++) {
    const int g = w * 4 + i;
    const size_t ga = (size_t)(bm * 128 + grow[i]) * DM + cp8;
    const size_t gb = (size_t)(bn * 128 + grow[i]) * DM + cp8;
    gl2lds16(Ahg + ga, &Ahs[0][0][0] + g * 512);
    gl2lds16(Bhg + gb, &Bhs[0][0][0] + g * 512);
    if (three) {
      gl2lds16(Alg + ga, &Als[0][0][0] + g * 512);
      gl2lds16(Blg + gb, &Bls[0][0][0] + g * 512);
    }
  }

  for (int t = 0; t < 16; t++) {
    const int cur = t & 1;
    __syncthreads();            // drains tile t loads (issued a full tile ago);
                                // all waves done reading buf[cur^1]
    if (t + 1 < 16) {
      const int kk = (t + 1) * 64, nxt = cur ^ 1;
      #pragma unroll
      for (int i = 0; i < 4; i++) {
        const int g = w * 4 + i;
        const size_t ga = (size_t)(bm * 128 + grow[i]) * DM + kk + cp8;
        const size_t gb = (size_t)(bn * 128 + grow[i]) * DM + kk + cp8;
        gl2lds16(Ahg + ga, &Ahs[nxt][0][0] + g * 512);
        gl2lds16(Bhg + gb, &Bhs[nxt][0][0] + g * 512);
        if (three) {
          gl2lds16(Alg + ga, &Als[nxt][0][0] + g * 512);
          gl2lds16(Blg + gb, &Bls[nxt][0][0] + g * 512);
        }
      }
    }

    #pragma unroll
    for (int kc = 0; kc < 2; kc++) {
      const int swz = ((kc * 4 + quad) ^ (l15 & 7)) * 8;
      half8 ah[4], bh_[4], al[4], bl[4];
      #pragma unroll
      for (int tt = 0; tt < 4; tt++) {
        ah[tt]  = *(const half8*)&Ahs[cur][wm * 64 + tt * 16 + l15][swz];
        bh_[tt] = *(const half8*)&Bhs[cur][wn * 64 + tt * 16 + l15][swz];
        if (three) {
          al[tt] = *(const half8*)&Als[cur][wm * 64 + tt * 16 + l15][swz];
          bl[tt] = *(const half8*)&Bls[cur][wn * 64 + tt * 16 + l15][swz];
        }
      }
      if (three) {
        #pragma unroll
        for (int mt = 0; mt < 4; mt++)
          #pragma unroll
          for (int nt = 0; nt < 4; nt++) {
            floatx4 t0 = MFMA_F16(ah[mt], bh_[nt], acc[mt][nt]);
            t0 = MFMA_F16(ah[mt], bl[nt], t0);
            acc[mt][nt] = MFMA_F16(al[mt], bh_[nt], t0);
          }
      } else {
        #pragma unroll
        for (int mt = 0; mt < 4; mt++)
          #pragma unroll
          for (int nt = 0; nt < 4; nt++)
            acc[mt][nt] = MFMA_F16(ah[mt], bh_[nt], acc[mt][nt]);
      }
    }
  }

  #pragma unroll
  for (int mt = 0; mt < 4; mt++)
    #pragma unroll
    for (int nt = 0; nt < 4; nt++)
      #pragma unroll
      for (int r = 0; r < 4; r++) {
        int gm = bm * 128 + wm * 64 + mt * 16 + quad * 4 + r;   // (b,s)
        int gn = bn * 128 + wn * 64 + nt * 16 + l15;            // h*64+d
        int b = gm >> 11, s = gm & 2047;
        int h = gn >> 6, d = gn & 63;
        size_t idx = ((size_t)(b * NH + h) * SEQ + s) * HD + d;
        float val = acc[mt][nt][r] * scale;
        _Float16 hi = (_Float16)val;
        yh[idx] = hi;
        if (three) yl[idx] = (_Float16)(val - (float)hi);
      }
}

// ---------------- vh [b,h,s,64] -> vhT [b,h,64,perm(s)] ----------------
// perm within 32-group: s = 32c+16a+4q+b -> pos = 32c+8q+4a+b, so flash PV
// A-fragments (key order 32kc+16(j>>2)+4quad+(j&3)) are contiguous b128 reads.
__global__ __launch_bounds__(256) void transpose_v(const _Float16* __restrict__ vh,
                                                   _Float16* __restrict__ vhT)
{
  __shared__ __align__(16) _Float16 T[128][72];
  const int bh = blockIdx.x, sc = blockIdx.y, tid = threadIdx.x;
  const _Float16* src = vh + ((size_t)bh * SEQ + sc * 128) * HD;
  #pragma unroll
  for (int i = 0; i < 4; i++) {
    int c = i * 256 + tid, row = c >> 3, off = (c & 7) * 8;
    *(half8*)&T[row][off] = *(const half8*)(src + (size_t)row * HD + off);
  }
  __syncthreads();
  _Float16* dst = vhT + (size_t)bh * HD * SEQ + sc * 128;
  #pragma unroll
  for (int i = 0; i < 4; i++) {
    int c = i * 256 + tid, hd = c >> 4, off = (c & 15) * 8;
    int base32 = off & ~31, qsel = (off >> 3) & 3;
    half8 vv;
    #pragma unroll
    for (int j = 0; j < 8; j++) {
      int s_local = base32 + 16 * (j >> 2) + 4 * qsel + (j & 3);
      vv[j] = T[s_local][hd];
    }
    *(half8*)(dst + (size_t)hd * SEQ + off) = vv;
  }
}

// ---------------- flash attention v10: XCD pin + split-K x2 + 2-phase stage --
// 1-D grid 1024 (R7 mapping); bh = (id&7) + 8*((id>>3)&3) pins K/V to one XCD L2.
// 4 waves, 32 q/wave. K hi/lo double-buffered, V single (40960 B LDS = 4 blk/CU).
// Per kt: barrier -> stage V(kt)+K(kt+1) -> QK^T+softmax+pack -> barrier(drain)
// -> av reads + PV. Every load gets a compute window before its drain.
__global__ __launch_bounds__(256, 4) void flash_kernel(
    const _Float16* __restrict__ qh_hi, const _Float16* __restrict__ qh_lo,
    const _Float16* __restrict__ kh_hi, const _Float16* __restrict__ kh_lo,
    const _Float16* __restrict__ vhT, float* __restrict__ Op, float2* __restrict__ ml)
{
  __shared__ __align__(16) _Float16 Kh[2][64][64];
  __shared__ __align__(16) _Float16 Kl[2][64][64];
  __shared__ __align__(16) _Float16 Vt[64][64];   // [d][permuted key]

  const int id = blockIdx.x;
  const int seq_ = id >> 3;
  const int bh = (id & 7) + 8 * (seq_ & 3);       // 0..31, pinned to XCD id&7
  const int rem = seq_ >> 2;
  const int qb = rem & 15;                        // 0..15
  const int kh = rem >> 4;                        // 0..1
  const int tid = threadIdx.x;
  const int wq = tid >> 6;
  const int lane = tid & 63, l15 = lane & 15, quad = lane >> 4;

  const size_t bh_off = (size_t)bh * SEQ * HD;
  const _Float16* __restrict__ kh_p = kh_hi + bh_off;
  const _Float16* __restrict__ kl_p = kh_lo + bh_off;
  const _Float16* __restrict__ vt_p = vhT + (size_t)bh * HD * SEQ;
  const int qrow0 = qb * 128 + wq * 32;

  // Q as B-operand fragments: lane holds n=q=l15, k=d=kc*32+quad*8+j
  half8 bqh[2][2], bql[2][2];         // [g][kc]
  #pragma unroll
  for (int g = 0; g < 2; g++) {
    const _Float16* qp_h = qh_hi + bh_off + (size_t)(qrow0 + g * 16 + l15) * HD;
    const _Float16* qp_l = qh_lo + bh_off + (size_t)(qrow0 + g * 16 + l15) * HD;
    #pragma unroll
    for (int kc = 0; kc < 2; kc++) {
      bqh[g][kc] = *(const half8*)(qp_h + kc * 32 + quad * 8);
      bql[g][kc] = *(const half8*)(qp_l + kc * 32 + quad * 8);
    }
  }

  // staging: wave wq covers groups 2wq, 2wq+1 per array (8 rows x 1 KiB each)
  const int r8 = lane >> 3;
  const int cp8 = ((lane & 7) ^ r8) * 8;

  float m_[2] = {-3.0e38f, -3.0e38f};
  float l_[2] = {0.f, 0.f};
  floatx4 Oacc[2][4];
  #pragma unroll
  for (int g = 0; g < 2; g++)
    #pragma unroll
    for (int nd = 0; nd < 4; nd++) Oacc[g][nd] = (floatx4){0.f, 0.f, 0.f, 0.f};

  const int kt0 = kh * 16;
  // prologue: stage K(kt0) into buffer 0
  {
    const int kbase = kt0 * 64;
    #pragma unroll
    for (int i = 0; i < 2; i++) {
      const int g = wq * 2 + i;
      const int r = g * 8 + r8;
      gl2lds16(kh_p + (size_t)(kbase + r) * HD + cp8, &Kh[0][0][0] + g * 512);
      gl2lds16(kl_p + (size_t)(kbase + r) * HD + cp8, &Kl[0][0][0] + g * 512);
    }
  }

  for (int kt = kt0; kt < kt0 + 16; kt++) {
    const int cur = kt & 1;                     // kt0 even -> prologue in buf 0
    const int kbase = kt * 64;
    __syncthreads();            // K(kt) visible; Vt free; Kbuf[cur^1] free

    // stage V(kt) and prefetch K(kt+1); both drain at the mid barrier below
    #pragma unroll
    for (int i = 0; i < 2; i++) {
      const int g = wq * 2 + i;
      const int r = g * 8 + r8;
      gl2lds16(vt_p + (size_t)r * SEQ + kbase + cp8, &Vt[0][0] + g * 512);
    }
    if (kt + 1 < kt0 + 16) {
      const int kb2 = (kt + 1) * 64, nxt = cur ^ 1;
      #pragma unroll
      for (int i = 0; i < 2; i++) {
        const int g = wq * 2 + i;
        const int r = g * 8 + r8;
        gl2lds16(kh_p + (size_t)(kb2 + r) * HD + cp8, &Kh[nxt][0][0] + g * 512);
        gl2lds16(kl_p + (size_t)(kb2 + r) * HD + cp8, &Kl[nxt][0][0] + g * 512);
      }
    }

    // S^T = K·Q^T (3-term split fp16), both q-groups share K fragments
    floatx4 sacc[2][4];
    const int r7 = l15 & 7;
    #pragma unroll
    for (int nt = 0; nt < 4; nt++) {
      half8 akh0 = *(const half8*)&Kh[cur][nt * 16 + l15][((0 * 4 + quad) ^ r7) * 8];
      half8 akh1 = *(const half8*)&Kh[cur][nt * 16 + l15][((1 * 4 + quad) ^ r7) * 8];
      half8 akl0 = *(const half8*)&Kl[cur][nt * 16 + l15][((0 * 4 + quad) ^ r7) * 8];
      half8 akl1 = *(const half8*)&Kl[cur][nt * 16 + l15][((1 * 4 + quad) ^ r7) * 8];
      #pragma unroll
      for (int g = 0; g < 2; g++) {
        floatx4 s4 = (floatx4){0.f, 0.f, 0.f, 0.f};
        s4 = MFMA_F16(akh0, bqh[g][0], s4);
        s4 = MFMA_F16(akh1, bqh[g][1], s4);
        s4 = MFMA_F16(akh0, bql[g][0], s4);
        s4 = MFMA_F16(akh1, bql[g][1], s4);
        s4 = MFMA_F16(akl0, bqh[g][0], s4);
        s4 = MFMA_F16(akl1, bqh[g][1], s4);
        sacc[g][nt] = s4;
      }
    }

    // online softmax + P pack for BOTH q-groups (before the drain barrier)
    float alpha2[2];
    half8 bp8g[2][2];
    #pragma unroll
    for (int g = 0; g < 2; g++) {
      float rmax = sacc[g][0][0];
      #pragma unroll
      for (int nt = 0; nt < 4; nt++)
        #pragma unroll
        for (int r = 0; r < 4; r++) rmax = fmaxf(rmax, sacc[g][nt][r]);
      rmax = fmaxf(rmax, __shfl_xor(rmax, 16, 64));
      rmax = fmaxf(rmax, __shfl_xor(rmax, 32, 64));
      const float mnew = fmaxf(m_[g], rmax);
      alpha2[g] = exp2f(m_[g] - mnew);
      m_[g] = mnew;

      float rsum = 0.f;
      #pragma unroll
      for (int nt = 0; nt < 4; nt++)
        #pragma unroll
        for (int r = 0; r < 4; r++) {
          float p = exp2f(sacc[g][nt][r] - mnew);
          sacc[g][nt][r] = p;
          rsum += p;
        }
      rsum += __shfl_xor(rsum, 16, 64);
      rsum += __shfl_xor(rsum, 32, 64);
      l_[g] = l_[g] * alpha2[g] + rsum;

      // P pack for PV B-operand: bp8g[g][kc][j] = p[2kc + (j>>2)][j&3] (in-lane)
      #pragma unroll
      for (int kc = 0; kc < 2; kc++)
        #pragma unroll
        for (int j = 0; j < 8; j++)
          bp8g[g][kc][j] = (_Float16)sacc[g][2 * kc + (j >> 2)][j & 3];
    }

    __syncthreads();            // V(kt) + K(kt+1) drained & visible

    // V A-fragments (permuted image), shared by both q-groups
    half8 av[4][2];
    #pragma unroll
    for (int nd = 0; nd < 4; nd++) {
      av[nd][0] = *(const half8*)&Vt[nd * 16 + l15][((0 * 4 + quad) ^ r7) * 8];
      av[nd][1] = *(const half8*)&Vt[nd * 16 + l15][((1 * 4 + quad) ^ r7) * 8];
    }

    #pragma unroll
    for (int g = 0; g < 2; g++) {
      #pragma unroll
      for (int nd = 0; nd < 4; nd++) {
        Oacc[g][nd][0] *= alpha2[g]; Oacc[g][nd][1] *= alpha2[g];
        Oacc[g][nd][2] *= alpha2[g]; Oacc[g][nd][3] *= alpha2[g];
        Oacc[g][nd] = MFMA_F16(av[nd][0], bp8g[g][0], Oacc[g][nd]);
        Oacc[g][nd] = MFMA_F16(av[nd][1], bp8g[g][1], Oacc[g][nd]);
      }
    }
  }

  // epilogue: unnormalized O^T partial + (m,l)
  const size_t fqbase = (size_t)bh * SEQ + qrow0;
  #pragma unroll
  for (int g = 0; g < 2; g++) {
    const size_t fq = fqbase + g * 16 + l15;
    float* ob = Op + ((size_t)kh * 65536 + fq) * HD;
    #pragma unroll
    for (int nd = 0; nd < 4; nd++) {
      float4 vv;
      vv.x = Oacc[g][nd][0]; vv.y = Oacc[g][nd][1];
      vv.z = Oacc[g][nd][2]; vv.w = Oacc[g][nd][3];
      *(float4*)(ob + nd * 16 + quad * 4) = vv;
    }
    if (quad == 0) ml[kh * 65536 + fq] = make_float2(m_[g], l_[g]);
  }
}

// ---------------- merge the two split-K partials ----------------
__global__ __launch_bounds__(256) void merge_kernel(const float* __restrict__ Op,
                                                    const float2* __restrict__ ml,
                                                    float* __restrict__ out)
{
  const int tid = threadIdx.x;
  const int fq = blockIdx.x * 64 + (tid >> 2);
  const int dp = (tid & 3) * 16;
  float2 m0 = ml[fq], m1 = ml[65536 + fq];
  float M = fmaxf(m0.x, m1.x);
  float w0 = exp2f(m0.x - M), w1 = exp2f(m1.x - M);
  float rinv = 1.0f / (m0.y * w0 + m1.y * w1);
  int bh = fq >> 11, s = fq & 2047, b = bh >> 4, h = bh & 15;
  float* ob = out + ((size_t)(b * SEQ + s)) * DM + h * HD + dp;
  const float* p0 = Op + (size_t)fq * HD + dp;
  const float* p1 = p0 + (size_t)65536 * HD;
  #pragma unroll
  for (int j = 0; j < 4; j++) {
    float4 a = *(const float4*)(p0 + 4 * j);
    float4 c = *(const float4*)(p1 + 4 * j);
    float4 r;
    r.x = (a.x * w0 + c.x * w1) * rinv;
    r.y = (a.y * w0 + c.y * w1) * rinv;
    r.z = (a.z * w0 + c.z * w1) * rinv;
    r.w = (a.w * w0 + c.w * w1) * rinv;
    *(float4*)(ob + 4 * j) = r;
  }
}

extern "C" void kernel_launch(void* const* d_in, const int* in_sizes, int n_in,
                              void* d_out, int out_size, void* d_ws, size_t ws_size,
                              hipStream_t stream) {
  const float* q  = (const float*)d_in[0];
  const float* k  = (const float*)d_in[1];
  const float* v  = (const float*)d_in[2];
  const float* Wq = (const float*)d_in[3];
  const float* Wk = (const float*)d_in[4];
  const float* Wv = (const float*)d_in[5];
  float* out = (float*)d_out;

  char* W = (char*)d_ws;
  const size_t MiB = 1ull << 20;
  _Float16* qh_hi = (_Float16*)(W + 0 * MiB);
  _Float16* qh_lo = (_Float16*)(W + 8 * MiB);
  _Float16* kh_hi = (_Float16*)(W + 16 * MiB);
  _Float16* kh_lo = (_Float16*)(W + 24 * MiB);
  _Float16* vhT   = (_Float16*)(W + 32 * MiB);
  _Float16* vh    = (_Float16*)(W + 40 * MiB);  // dead after transpose_v
  _Float16* xh    = (_Float16*)(W + 48 * MiB);  // dead after last proj
  _Float16* xl    = (_Float16*)(W + 56 * MiB);
  _Float16* Wh    = (_Float16*)(W + 64 * MiB);
  _Float16* Wl    = (_Float16*)(W + 66 * MiB);
  float*    Op    = (float*)  (W + 40 * MiB);   // 2 x 16 MiB, aliases vh/xh/xl/Wh/Wl
  float2*   mlp   = (float2*) (W + 72 * MiB);   // 1 MiB; total 73 MiB

  // Q
  convert_kernel<<<5120, 256, 0, stream>>>(q, Wq, xh, xl, Wh, Wl, 1);
  proj_kernel<<<dim3(32, 8), 256, 0, stream>>>(xh, xl, Wh, Wl, qh_hi, qh_lo, QSCALE, 1);
  // K
  convert_kernel<<<5120, 256, 0, stream>>>(k, Wk, xh, xl, Wh, Wl, 1);
  proj_kernel<<<dim3(32, 8), 256, 0, stream>>>(xh, xl, Wh, Wl, kh_hi, kh_lo, 1.0f, 1);
  // V (single-term)
  convert_kernel<<<5120, 256, 0, stream>>>(v, Wv, xh, xl, Wh, Wl, 0);
  proj_kernel<<<dim3(32, 8), 256, 0, stream>>>(xh, xl, Wh, Wl, vh, vh, 1.0f, 0);

  transpose_v<<<dim3(32, 16), 256, 0, stream>>>(vh, vhT);
  flash_kernel<<<1024, 256, 0, stream>>>(qh_hi, qh_lo, kh_hi, kh_lo, vhT, Op, mlp);
  merge_kernel<<<1024, 256, 0, stream>>>(Op, mlp, out);
}

// Round 4
// 295.421 us; speedup vs baseline: 1.7556x; 1.0901x over previous
//
#include <hip/hip_runtime.h>

// MultiHeadAttention: B=2, S=2048, D=1024, H=16, HD=64, scores MULTIPLIED by 64.
// Round 11: R10 post-mortem — dbuf was neutral (staging latency already hidden
// by co-resident waves); proj's real deficit is 1 block/CU (grid 256). Fix by
// FUSING the three independent projections into ONE launch: grid (32,8,3) =
// 768 blocks -> 2 blocks/CU (LDS 64 KiB caps at 2), cross-block latency hiding.
// proj body reverted to R7 single-buffer. Converts fused into one launch.
// flash = R10 structure + T5 s_setprio around MFMA clusters (attn +4-7%, m191).
// 9 launches -> 5.
// LDS image: row r, logical chunk c stored at col (c ^ (r&7)) -- 2-way banks (free).
// Workspace 99 MiB: 0 qh_hi | 8 qh_lo | 16 kh_hi | 24 kh_lo | 32 vhT | 40 vh |
//   48 xq_h | 56 xq_l | 64 xk_h | 72 xk_l | 80 xv_h | 88 Wqh | 90 Wql | 92 Wkh |
//   94 Wkl | 96 Wvh ; Op 40..72 (aliases vh/xq_h/xq_l, dead by flash) ; 98 ml.

typedef _Float16 half4 __attribute__((ext_vector_type(4)));
typedef _Float16 half8 __attribute__((ext_vector_type(8)));
typedef float floatx4 __attribute__((ext_vector_type(4)));

#define MFMA_F16(a, b, c) __builtin_amdgcn_mfma_f32_16x16x32_f16((a), (b), (c), 0, 0, 0)

constexpr int SEQ = 2048;
constexpr int DM = 1024;
constexpr int NH = 16;
constexpr int HD = 64;
// 64 * log2(e): fold score scale + base-2 conversion into Q projection
constexpr float QSCALE = 92.33248261689366f;

// async 16B/lane global->LDS copy; LDS dest = wave-uniform base + lane*16
__device__ __forceinline__ void gl2lds16(const _Float16* g, _Float16* l) {
  __builtin_amdgcn_global_load_lds(
      (const __attribute__((address_space(1))) void*)g,
      (__attribute__((address_space(3))) void*)l, 16, 0, 0);
}

__device__ inline void split4(const float4 f, half4& h, half4& l) {
  h[0] = (_Float16)f.x; l[0] = (_Float16)(f.x - (float)h[0]);
  h[1] = (_Float16)f.y; l[1] = (_Float16)(f.y - (float)h[1]);
  h[2] = (_Float16)f.z; l[2] = (_Float16)(f.z - (float)h[2]);
  h[3] = (_Float16)f.w; l[3] = (_Float16)(f.w - (float)h[3]);
}

// ---------------- fused convert: all six fp32 tensors -> fp16 hi (+lo) ------
// blocks: 0..4095 q | 4096..8191 k | 8192..12287 v | 12288..13311 Wq |
//         13312..14335 Wk | 14336..15359 Wv.  v/Wv: hi only.
__global__ __launch_bounds__(256) void convert_all(
    const float* __restrict__ q, const float* __restrict__ k,
    const float* __restrict__ v, const float* __restrict__ Wq,
    const float* __restrict__ Wk, const float* __restrict__ Wv,
    _Float16* __restrict__ xq_h, _Float16* __restrict__ xq_l,
    _Float16* __restrict__ xk_h, _Float16* __restrict__ xk_l,
    _Float16* __restrict__ xv_h,
    _Float16* __restrict__ Wqh, _Float16* __restrict__ Wql,
    _Float16* __restrict__ Wkh, _Float16* __restrict__ Wkl,
    _Float16* __restrict__ Wvh)
{
  const int bid = blockIdx.x;
  const float* src; _Float16* dh; _Float16* dl; int do_lo, i0;
  if (bid < 4096)       { src = q;  dh = xq_h; dl = xq_l; do_lo = 1; i0 = bid; }
  else if (bid < 8192)  { src = k;  dh = xk_h; dl = xk_l; do_lo = 1; i0 = bid - 4096; }
  else if (bid < 12288) { src = v;  dh = xv_h; dl = xv_h; do_lo = 0; i0 = bid - 8192; }
  else if (bid < 13312) { src = Wq; dh = Wqh;  dl = Wql;  do_lo = 1; i0 = bid - 12288; }
  else if (bid < 14336) { src = Wk; dh = Wkh;  dl = Wkl;  do_lo = 1; i0 = bid - 13312; }
  else                  { src = Wv; dh = Wvh;  dl = Wvh;  do_lo = 0; i0 = bid - 14336; }
  const int idx = i0 * 256 + threadIdx.x;
  float4 f = ((const float4*)src)[idx];
  half4 h, l; split4(f, h, l);
  *(half4*)(dh + (size_t)idx * 4) = h;
  if (do_lo) *(half4*)(dl + (size_t)idx * 4) = l;
}

// ---------------- fused projection GEMMs: y = A @ B^T (pre-converted fp16) --
// 128x128 tile, BK=64, global_load_lds staging, single-buffered (64 KiB LDS ->
// 2 blocks/CU). Grid (32,8,3): z selects {Q,K,V} projection; 768 blocks total
// give cross-block latency hiding that the old 256-block launch lacked.
// Q/K: 3-term split-fp16, write yh+yl; V: single-term, yh only.
__global__ __launch_bounds__(256, 1) void proj3_kernel(
    const _Float16* __restrict__ xq_h, const _Float16* __restrict__ xq_l,
    const _Float16* __restrict__ xk_h, const _Float16* __restrict__ xk_l,
    const _Float16* __restrict__ xv_h,
    const _Float16* __restrict__ Wqh, const _Float16* __restrict__ Wql,
    const _Float16* __restrict__ Wkh, const _Float16* __restrict__ Wkl,
    const _Float16* __restrict__ Wvh,
    _Float16* __restrict__ qh_hi, _Float16* __restrict__ qh_lo,
    _Float16* __restrict__ kh_hi, _Float16* __restrict__ kh_lo,
    _Float16* __restrict__ vh)
{
  __shared__ __align__(16) _Float16 Ahs[128][64];
  __shared__ __align__(16) _Float16 Als[128][64];
  __shared__ __align__(16) _Float16 Bhs[128][64];
  __shared__ __align__(16) _Float16 Bls[128][64];

  const int z = blockIdx.z;
  const _Float16 *Ahg, *Alg, *Bhg, *Blg;
  _Float16 *yh, *yl;
  float scale; int three;
  if (z == 0)      { Ahg = xq_h; Alg = xq_l; Bhg = Wqh; Blg = Wql;
                     yh = qh_hi; yl = qh_lo; scale = QSCALE; three = 1; }
  else if (z == 1) { Ahg = xk_h; Alg = xk_l; Bhg = Wkh; Blg = Wkl;
                     yh = kh_hi; yl = kh_lo; scale = 1.0f; three = 1; }
  else             { Ahg = xv_h; Alg = xv_h; Bhg = Wvh; Blg = Wvh;
                     yh = vh;    yl = vh;    scale = 1.0f; three = 0; }

  const int tid = threadIdx.x;
  const int bm = blockIdx.x;          // 0..31
  const int bn = blockIdx.y;          // 0..7
  const int lane = tid & 63, l15 = lane & 15, quad = lane >> 4;
  const int w = tid >> 6, wm = w >> 1, wn = w & 1;

  // staging: wave w stages groups g = 4w+i (8 rows x 1 KiB each) of each array.
  // lane L: row-in-group = L>>3, fetches logical chunk (L&7)^(L>>3) -> XOR image.
  const int r8 = lane >> 3;
  const int cp8 = (((lane & 7) ^ r8)) * 8;    // half offset within row
  int grow[4]; _Float16* la[4]; _Float16* lal[4]; _Float16* lb[4]; _Float16* lbl[4];
  #pragma unroll
  for (int i = 0; i < 4; i++) {
    const int g = w * 4 + i;
    grow[i] = g * 8 + r8;                     // row 0..127 (per-lane)
    la[i]  = &Ahs[0][0] + g * 512;            // wave-uniform LDS bases
    lal[i] = &Als[0][0] + g * 512;
    lb[i]  = &Bhs[0][0] + g * 512;
    lbl[i] = &Bls[0][0] + g * 512;
  }

  floatx4 acc[4][4];
  #pragma unroll
  for (int mt = 0; mt < 4; mt++)
    #pragma unroll
    for (int nt = 0; nt < 4; nt++)
      acc[mt][nt] = (floatx4){0.f, 0.f, 0.f, 0.f};

  for (int kk = 0; kk < DM; kk += 64) {
    __syncthreads();                          // prior tile's reads complete
    #pragma unroll
    for (int i = 0; i < 4; i++) {
      const size_t ga = (size_t)(bm * 128 + grow[i]) * DM + kk + cp8;
      const size_t gb = (size_t)(bn * 128 + grow[i]) * DM + kk + cp8;
      gl2lds16(Ahg + ga, la[i]);
      gl2lds16(Bhg + gb, lb[i]);
      if (three) {
        gl2lds16(Alg + ga, lal[i]);
        gl2lds16(Blg + gb, lbl[i]);
      }
    }
    __syncthreads();                          // vmcnt(0) drain: tile visible

    #pragma unroll
    for (int kc = 0; kc < 2; kc++) {
      const int swz = ((kc * 4 + quad) ^ (l15 & 7)) * 8;
      half8 ah[4], bh_[4], al[4], bl[4];
      #pragma unroll
      for (int t = 0; t < 4; t++) {
        ah[t]  = *(const half8*)&Ahs[wm * 64 + t * 16 + l15][swz];
        bh_[t] = *(const half8*)&Bhs[wn * 64 + t * 16 + l15][swz];
        if (three) {
          al[t] = *(const half8*)&Als[wm * 64 + t * 16 + l15][swz];
          bl[t] = *(const half8*)&Bls[wn * 64 + t * 16 + l15][swz];
        }
      }
      if (three) {
        #pragma unroll
        for (int mt = 0; mt < 4; mt++)
          #pragma unroll
          for (int nt = 0; nt < 4; nt++) {
            floatx4 t0 = MFMA_F16(ah[mt], bh_[nt], acc[mt][nt]);
            t0 = MFMA_F16(ah[mt], bl[nt], t0);
            acc[mt][nt] = MFMA_F16(al[mt], bh_[nt], t0);
          }
      } else {
        #pragma unroll
        for (int mt = 0; mt < 4; mt++)
          #pragma unroll
          for (int nt = 0; nt < 4; nt++)
            acc[mt][nt] = MFMA_F16(ah[mt], bh_[nt], acc[mt][nt]);
      }
    }
  }

  #pragma unroll
  for (int mt = 0; mt < 4; mt++)
    #pragma unroll
    for (int nt = 0; nt < 4; nt++)
      #pragma unroll
      for (int r = 0; r < 4; r++) {
        int gm = bm * 128 + wm * 64 + mt * 16 + quad * 4 + r;   // (b,s)
        int gn = bn * 128 + wn * 64 + nt * 16 + l15;            // h*64+d
        int b = gm >> 11, s = gm & 2047;
        int h = gn >> 6, d = gn & 63;
        size_t idx = ((size_t)(b * NH + h) * SEQ + s) * HD + d;
        float val = acc[mt][nt][r] * scale;
        _Float16 hi = (_Float16)val;
        yh[idx] = hi;
        if (three) yl[idx] = (_Float16)(val - (float)hi);
      }
}

// ---------------- vh [b,h,s,64] -> vhT [b,h,64,perm(s)] ----------------
// perm within 32-group: s = 32c+16a+4q+b -> pos = 32c+8q+4a+b, so flash PV
// A-fragments (key order 32kc+16(j>>2)+4quad+(j&3)) are contiguous b128 reads.
__global__ __launch_bounds__(256) void transpose_v(const _Float16* __restrict__ vh,
                                                   _Float16* __restrict__ vhT)
{
  __shared__ __align__(16) _Float16 T[128][72];
  const int bh = blockIdx.x, sc = blockIdx.y, tid = threadIdx.x;
  const _Float16* src = vh + ((size_t)bh * SEQ + sc * 128) * HD;
  #pragma unroll
  for (int i = 0; i < 4; i++) {
    int c = i * 256 + tid, row = c >> 3, off = (c & 7) * 8;
    *(half8*)&T[row][off] = *(const half8*)(src + (size_t)row * HD + off);
  }
  __syncthreads();
  _Float16* dst = vhT + (size_t)bh * HD * SEQ + sc * 128;
  #pragma unroll
  for (int i = 0; i < 4; i++) {
    int c = i * 256 + tid, hd = c >> 4, off = (c & 15) * 8;
    int base32 = off & ~31, qsel = (off >> 3) & 3;
    half8 vv;
    #pragma unroll
    for (int j = 0; j < 8; j++) {
      int s_local = base32 + 16 * (j >> 2) + 4 * qsel + (j & 3);
      vv[j] = T[s_local][hd];
    }
    *(half8*)(dst + (size_t)hd * SEQ + off) = vv;
  }
}

// ---------------- flash attention v11: R10 structure + T5 setprio ----------
// 1-D grid 1024; bh = (id&7) + 8*((id>>3)&3) pins each bh's K/V to one XCD L2.
// 4 waves, 32 q/wave. K hi/lo double-buffered, V single (40960 B LDS).
// Per kt: barrier -> stage V(kt)+K(kt+1) -> QK^T+softmax+pack -> barrier(drain)
// -> av reads + PV. s_setprio(1) wraps the MFMA clusters (m191: attn +4-7%).
__global__ __launch_bounds__(256, 4) void flash_kernel(
    const _Float16* __restrict__ qh_hi, const _Float16* __restrict__ qh_lo,
    const _Float16* __restrict__ kh_hi, const _Float16* __restrict__ kh_lo,
    const _Float16* __restrict__ vhT, float* __restrict__ Op, float2* __restrict__ ml)
{
  __shared__ __align__(16) _Float16 Kh[2][64][64];
  __shared__ __align__(16) _Float16 Kl[2][64][64];
  __shared__ __align__(16) _Float16 Vt[64][64];   // [d][permuted key]

  const int id = blockIdx.x;
  const int seq_ = id >> 3;
  const int bh = (id & 7) + 8 * (seq_ & 3);       // 0..31, pinned to XCD id&7
  const int rem = seq_ >> 2;
  const int qb = rem & 15;                        // 0..15
  const int kh = rem >> 4;                        // 0..1
  const int tid = threadIdx.x;
  const int wq = tid >> 6;
  const int lane = tid & 63, l15 = lane & 15, quad = lane >> 4;

  const size_t bh_off = (size_t)bh * SEQ * HD;
  const _Float16* __restrict__ kh_p = kh_hi + bh_off;
  const _Float16* __restrict__ kl_p = kh_lo + bh_off;
  const _Float16* __restrict__ vt_p = vhT + (size_t)bh * HD * SEQ;
  const int qrow0 = qb * 128 + wq * 32;

  // Q as B-operand fragments: lane holds n=q=l15, k=d=kc*32+quad*8+j
  half8 bqh[2][2], bql[2][2];         // [g][kc]
  #pragma unroll
  for (int g = 0; g < 2; g++) {
    const _Float16* qp_h = qh_hi + bh_off + (size_t)(qrow0 + g * 16 + l15) * HD;
    const _Float16* qp_l = qh_lo + bh_off + (size_t)(qrow0 + g * 16 + l15) * HD;
    #pragma unroll
    for (int kc = 0; kc < 2; kc++) {
      bqh[g][kc] = *(const half8*)(qp_h + kc * 32 + quad * 8);
      bql[g][kc] = *(const half8*)(qp_l + kc * 32 + quad * 8);
    }
  }

  // staging: wave wq covers groups 2wq, 2wq+1 per array (8 rows x 1 KiB each)
  const int r8 = lane >> 3;
  const int cp8 = ((lane & 7) ^ r8) * 8;

  float m_[2] = {-3.0e38f, -3.0e38f};
  float l_[2] = {0.f, 0.f};
  floatx4 Oacc[2][4];
  #pragma unroll
  for (int g = 0; g < 2; g++)
    #pragma unroll
    for (int nd = 0; nd < 4; nd++) Oacc[g][nd] = (floatx4){0.f, 0.f, 0.f, 0.f};

  const int kt0 = kh * 16;
  // prologue: stage K(kt0) into buffer 0
  {
    const int kbase = kt0 * 64;
    #pragma unroll
    for (int i = 0; i < 2; i++) {
      const int g = wq * 2 + i;
      const int r = g * 8 + r8;
      gl2lds16(kh_p + (size_t)(kbase + r) * HD + cp8, &Kh[0][0][0] + g * 512);
      gl2lds16(kl_p + (size_t)(kbase + r) * HD + cp8, &Kl[0][0][0] + g * 512);
    }
  }

  for (int kt = kt0; kt < kt0 + 16; kt++) {
    const int cur = kt & 1;                     // kt0 even -> prologue in buf 0
    const int kbase = kt * 64;
    __syncthreads();            // K(kt) visible; Vt free; Kbuf[cur^1] free

    // stage V(kt) and prefetch K(kt+1); both drain at the mid barrier below
    #pragma unroll
    for (int i = 0; i < 2; i++) {
      const int g = wq * 2 + i;
      const int r = g * 8 + r8;
      gl2lds16(vt_p + (size_t)r * SEQ + kbase + cp8, &Vt[0][0] + g * 512);
    }
    if (kt + 1 < kt0 + 16) {
      const int kb2 = (kt + 1) * 64, nxt = cur ^ 1;
      #pragma unroll
      for (int i = 0; i < 2; i++) {
        const int g = wq * 2 + i;
        const int r = g * 8 + r8;
        gl2lds16(kh_p + (size_t)(kb2 + r) * HD + cp8, &Kh[nxt][0][0] + g * 512);
        gl2lds16(kl_p + (size_t)(kb2 + r) * HD + cp8, &Kl[nxt][0][0] + g * 512);
      }
    }

    // S^T = K·Q^T (3-term split fp16), both q-groups share K fragments
    floatx4 sacc[2][4];
    const int r7 = l15 & 7;
    __builtin_amdgcn_s_setprio(1);
    #pragma unroll
    for (int nt = 0; nt < 4; nt++) {
      half8 akh0 = *(const half8*)&Kh[cur][nt * 16 + l15][((0 * 4 + quad) ^ r7) * 8];
      half8 akh1 = *(const half8*)&Kh[cur][nt * 16 + l15][((1 * 4 + quad) ^ r7) * 8];
      half8 akl0 = *(const half8*)&Kl[cur][nt * 16 + l15][((0 * 4 + quad) ^ r7) * 8];
      half8 akl1 = *(const half8*)&Kl[cur][nt * 16 + l15][((1 * 4 + quad) ^ r7) * 8];
      #pragma unroll
      for (int g = 0; g < 2; g++) {
        floatx4 s4 = (floatx4){0.f, 0.f, 0.f, 0.f};
        s4 = MFMA_F16(akh0, bqh[g][0], s4);
        s4 = MFMA_F16(akh1, bqh[g][1], s4);
        s4 = MFMA_F16(akh0, bql[g][0], s4);
        s4 = MFMA_F16(akh1, bql[g][1], s4);
        s4 = MFMA_F16(akl0, bqh[g][0], s4);
        s4 = MFMA_F16(akl1, bqh[g][1], s4);
        sacc[g][nt] = s4;
      }
    }
    __builtin_amdgcn_s_setprio(0);

    // online softmax + P pack for BOTH q-groups (before the drain barrier)
    float alpha2[2];
    half8 bp8g[2][2];
    #pragma unroll
    for (int g = 0; g < 2; g++) {
      float rmax = sacc[g][0][0];
      #pragma unroll
      for (int nt = 0; nt < 4; nt++)
        #pragma unroll
        for (int r = 0; r < 4; r++) rmax = fmaxf(rmax, sacc[g][nt][r]);
      rmax = fmaxf(rmax, __shfl_xor(rmax, 16, 64));
      rmax = fmaxf(rmax, __shfl_xor(rmax, 32, 64));
      const float mnew = fmaxf(m_[g], rmax);
      alpha2[g] = exp2f(m_[g] - mnew);
      m_[g] = mnew;

      float rsum = 0.f;
      #pragma unroll
      for (int nt = 0; nt < 4; nt++)
        #pragma unroll
        for (int r = 0; r < 4; r++) {
          float p = exp2f(sacc[g][nt][r] - mnew);
          sacc[g][nt][r] = p;
          rsum += p;
        }
      rsum += __shfl_xor(rsum, 16, 64);
      rsum += __shfl_xor(rsum, 32, 64);
      l_[g] = l_[g] * alpha2[g] + rsum;

      // P pack for PV B-operand: bp8g[g][kc][j] = p[2kc + (j>>2)][j&3] (in-lane)
      #pragma unroll
      for (int kc = 0; kc < 2; kc++)
        #pragma unroll
        for (int j = 0; j < 8; j++)
          bp8g[g][kc][j] = (_Float16)sacc[g][2 * kc + (j >> 2)][j & 3];
    }

    __syncthreads();            // V(kt) + K(kt+1) drained & visible

    // V A-fragments (permuted image), shared by both q-groups
    half8 av[4][2];
    #pragma unroll
    for (int nd = 0; nd < 4; nd++) {
      av[nd][0] = *(const half8*)&Vt[nd * 16 + l15][((0 * 4 + quad) ^ r7) * 8];
      av[nd][1] = *(const half8*)&Vt[nd * 16 + l15][((1 * 4 + quad) ^ r7) * 8];
    }

    __builtin_amdgcn_s_setprio(1);
    #pragma unroll
    for (int g = 0; g < 2; g++) {
      #pragma unroll
      for (int nd = 0; nd < 4; nd++) {
        Oacc[g][nd][0] *= alpha2[g]; Oacc[g][nd][1] *= alpha2[g];
        Oacc[g][nd][2] *= alpha2[g]; Oacc[g][nd][3] *= alpha2[g];
        Oacc[g][nd] = MFMA_F16(av[nd][0], bp8g[g][0], Oacc[g][nd]);
        Oacc[g][nd] = MFMA_F16(av[nd][1], bp8g[g][1], Oacc[g][nd]);
      }
    }
    __builtin_amdgcn_s_setprio(0);
  }

  // epilogue: unnormalized O^T partial + (m,l)
  const size_t fqbase = (size_t)bh * SEQ + qrow0;
  #pragma unroll
  for (int g = 0; g < 2; g++) {
    const size_t fq = fqbase + g * 16 + l15;
    float* ob = Op + ((size_t)kh * 65536 + fq) * HD;
    #pragma unroll
    for (int nd = 0; nd < 4; nd++) {
      float4 vv;
      vv.x = Oacc[g][nd][0]; vv.y = Oacc[g][nd][1];
      vv.z = Oacc[g][nd][2]; vv.w = Oacc[g][nd][3];
      *(float4*)(ob + nd * 16 + quad * 4) = vv;
    }
    if (quad == 0) ml[kh * 65536 + fq] = make_float2(m_[g], l_[g]);
  }
}

// ---------------- merge the two split-K partials ----------------
__global__ __launch_bounds__(256) void merge_kernel(const float* __restrict__ Op,
                                                    const float2* __restrict__ ml,
                                                    float* __restrict__ out)
{
  const int tid = threadIdx.x;
  const int fq = blockIdx.x * 64 + (tid >> 2);
  const int dp = (tid & 3) * 16;
  float2 m0 = ml[fq], m1 = ml[65536 + fq];
  float M = fmaxf(m0.x, m1.x);
  float w0 = exp2f(m0.x - M), w1 = exp2f(m1.x - M);
  float rinv = 1.0f / (m0.y * w0 + m1.y * w1);
  int bh = fq >> 11, s = fq & 2047, b = bh >> 4, h = bh & 15;
  float* ob = out + ((size_t)(b * SEQ + s)) * DM + h * HD + dp;
  const float* p0 = Op + (size_t)fq * HD + dp;
  const float* p1 = p0 + (size_t)65536 * HD;
  #pragma unroll
  for (int j = 0; j < 4; j++) {
    float4 a = *(const float4*)(p0 + 4 * j);
    float4 c = *(const float4*)(p1 + 4 * j);
    float4 r;
    r.x = (a.x * w0 + c.x * w1) * rinv;
    r.y = (a.y * w0 + c.y * w1) * rinv;
    r.z = (a.z * w0 + c.z * w1) * rinv;
    r.w = (a.w * w0 + c.w * w1) * rinv;
    *(float4*)(ob + 4 * j) = r;
  }
}

extern "C" void kernel_launch(void* const* d_in, const int* in_sizes, int n_in,
                              void* d_out, int out_size, void* d_ws, size_t ws_size,
                              hipStream_t stream) {
  const float* q  = (const float*)d_in[0];
  const float* k  = (const float*)d_in[1];
  const float* v  = (const float*)d_in[2];
  const float* Wq = (const float*)d_in[3];
  const float* Wk = (const float*)d_in[4];
  const float* Wv = (const float*)d_in[5];
  float* out = (float*)d_out;

  char* W = (char*)d_ws;
  const size_t MiB = 1ull << 20;
  _Float16* qh_hi = (_Float16*)(W + 0 * MiB);
  _Float16* qh_lo = (_Float16*)(W + 8 * MiB);
  _Float16* kh_hi = (_Float16*)(W + 16 * MiB);
  _Float16* kh_lo = (_Float16*)(W + 24 * MiB);
  _Float16* vhT   = (_Float16*)(W + 32 * MiB);
  _Float16* vh    = (_Float16*)(W + 40 * MiB);  // dead after transpose_v
  _Float16* xq_h  = (_Float16*)(W + 48 * MiB);  // dead after proj3
  _Float16* xq_l  = (_Float16*)(W + 56 * MiB);
  _Float16* xk_h  = (_Float16*)(W + 64 * MiB);
  _Float16* xk_l  = (_Float16*)(W + 72 * MiB);
  _Float16* xv_h  = (_Float16*)(W + 80 * MiB);
  _Float16* Wqh   = (_Float16*)(W + 88 * MiB);
  _Float16* Wql   = (_Float16*)(W + 90 * MiB);
  _Float16* Wkh   = (_Float16*)(W + 92 * MiB);
  _Float16* Wkl   = (_Float16*)(W + 94 * MiB);
  _Float16* Wvh   = (_Float16*)(W + 96 * MiB);
  float*    Op    = (float*)  (W + 40 * MiB);   // 2 x 16 MiB, aliases vh/xq_h/xq_l
  float2*   mlp   = (float2*) (W + 98 * MiB);   // 1 MiB; total 99 MiB

  convert_all<<<15360, 256, 0, stream>>>(q, k, v, Wq, Wk, Wv,
                                         xq_h, xq_l, xk_h, xk_l, xv_h,
                                         Wqh, Wql, Wkh, Wkl, Wvh);
  proj3_kernel<<<dim3(32, 8, 3), 256, 0, stream>>>(
      xq_h, xq_l, xk_h, xk_l, xv_h, Wqh, Wql, Wkh, Wkl, Wvh,
      qh_hi, qh_lo, kh_hi, kh_lo, vh);
  transpose_v<<<dim3(32, 16), 256, 0, stream>>>(vh, vhT);
  flash_kernel<<<1024, 256, 0, stream>>>(qh_hi, qh_lo, kh_hi, kh_lo, vhT, Op, mlp);
  merge_kernel<<<1024, 256, 0, stream>>>(Op, mlp, out);
}

// Round 5
// 293.206 us; speedup vs baseline: 1.7689x; 1.0076x over previous
//
#include <hip/hip_runtime.h>

// MultiHeadAttention: B=2, S=2048, D=1024, H=16, HD=64, scores MULTIPLIED by 64.
// Round 12: consolidation. (1) flash reverted to R10 body — R11's setprio was
// -4% (lockstep waves, no role-split: m190-style null-to-negative). (2)
// transpose_v DELETED: proj3's V epilogue writes vhT directly (per-thread
// acc[mt][nt][0..3] is 4 consecutive s at fixed d -> one aligned half4 at
// [bh][d][perm(s)], perm: s=32c+16a+4q+b -> pos=32c+8q+4a+b). 5 launches -> 4.
// LDS image: row r, logical chunk c stored at col (c ^ (r&7)) -- 2-way banks (free).
// Workspace 99 MiB: 0 qh_hi | 8 qh_lo | 16 kh_hi | 24 kh_lo | 32 vhT | 40 (Op) |
//   48 xq_h | 56 xq_l | 64 xk_h | 72 xk_l | 80 xv_h | 88 Wqh | 90 Wql | 92 Wkh |
//   94 Wkl | 96 Wvh ; Op 40..72 (aliases xq slots? no: 40..72 spans old vh/xq_h/
//   xq_l regions, all dead by flash) ; 98 ml.

typedef _Float16 half4 __attribute__((ext_vector_type(4)));
typedef _Float16 half8 __attribute__((ext_vector_type(8)));
typedef float floatx4 __attribute__((ext_vector_type(4)));

#define MFMA_F16(a, b, c) __builtin_amdgcn_mfma_f32_16x16x32_f16((a), (b), (c), 0, 0, 0)

constexpr int SEQ = 2048;
constexpr int DM = 1024;
constexpr int NH = 16;
constexpr int HD = 64;
// 64 * log2(e): fold score scale + base-2 conversion into Q projection
constexpr float QSCALE = 92.33248261689366f;

// async 16B/lane global->LDS copy; LDS dest = wave-uniform base + lane*16
__device__ __forceinline__ void gl2lds16(const _Float16* g, _Float16* l) {
  __builtin_amdgcn_global_load_lds(
      (const __attribute__((address_space(1))) void*)g,
      (__attribute__((address_space(3))) void*)l, 16, 0, 0);
}

__device__ inline void split4(const float4 f, half4& h, half4& l) {
  h[0] = (_Float16)f.x; l[0] = (_Float16)(f.x - (float)h[0]);
  h[1] = (_Float16)f.y; l[1] = (_Float16)(f.y - (float)h[1]);
  h[2] = (_Float16)f.z; l[2] = (_Float16)(f.z - (float)h[2]);
  h[3] = (_Float16)f.w; l[3] = (_Float16)(f.w - (float)h[3]);
}

// ---------------- fused convert: all six fp32 tensors -> fp16 hi (+lo) ------
// blocks: 0..4095 q | 4096..8191 k | 8192..12287 v | 12288..13311 Wq |
//         13312..14335 Wk | 14336..15359 Wv.  v/Wv: hi only.
__global__ __launch_bounds__(256) void convert_all(
    const float* __restrict__ q, const float* __restrict__ k,
    const float* __restrict__ v, const float* __restrict__ Wq,
    const float* __restrict__ Wk, const float* __restrict__ Wv,
    _Float16* __restrict__ xq_h, _Float16* __restrict__ xq_l,
    _Float16* __restrict__ xk_h, _Float16* __restrict__ xk_l,
    _Float16* __restrict__ xv_h,
    _Float16* __restrict__ Wqh, _Float16* __restrict__ Wql,
    _Float16* __restrict__ Wkh, _Float16* __restrict__ Wkl,
    _Float16* __restrict__ Wvh)
{
  const int bid = blockIdx.x;
  const float* src; _Float16* dh; _Float16* dl; int do_lo, i0;
  if (bid < 4096)       { src = q;  dh = xq_h; dl = xq_l; do_lo = 1; i0 = bid; }
  else if (bid < 8192)  { src = k;  dh = xk_h; dl = xk_l; do_lo = 1; i0 = bid - 4096; }
  else if (bid < 12288) { src = v;  dh = xv_h; dl = xv_h; do_lo = 0; i0 = bid - 8192; }
  else if (bid < 13312) { src = Wq; dh = Wqh;  dl = Wql;  do_lo = 1; i0 = bid - 12288; }
  else if (bid < 14336) { src = Wk; dh = Wkh;  dl = Wkl;  do_lo = 1; i0 = bid - 13312; }
  else                  { src = Wv; dh = Wvh;  dl = Wvh;  do_lo = 0; i0 = bid - 14336; }
  const int idx = i0 * 256 + threadIdx.x;
  float4 f = ((const float4*)src)[idx];
  half4 h, l; split4(f, h, l);
  *(half4*)(dh + (size_t)idx * 4) = h;
  if (do_lo) *(half4*)(dl + (size_t)idx * 4) = l;
}

// ---------------- fused projection GEMMs: y = A @ B^T (pre-converted fp16) --
// 128x128 tile, BK=64, global_load_lds staging, single-buffered (64 KiB LDS ->
// 2 blocks/CU). Grid (32,8,3): z selects {Q,K,V}. Q/K: 3-term split-fp16,
// scalar hi/lo epilogue. V: single-term, epilogue writes vhT DIRECTLY in the
// flash-permuted transposed layout (half4 stores; transpose_v kernel deleted).
__global__ __launch_bounds__(256, 1) void proj3_kernel(
    const _Float16* __restrict__ xq_h, const _Float16* __restrict__ xq_l,
    const _Float16* __restrict__ xk_h, const _Float16* __restrict__ xk_l,
    const _Float16* __restrict__ xv_h,
    const _Float16* __restrict__ Wqh, const _Float16* __restrict__ Wql,
    const _Float16* __restrict__ Wkh, const _Float16* __restrict__ Wkl,
    const _Float16* __restrict__ Wvh,
    _Float16* __restrict__ qh_hi, _Float16* __restrict__ qh_lo,
    _Float16* __restrict__ kh_hi, _Float16* __restrict__ kh_lo,
    _Float16* __restrict__ vhT)
{
  __shared__ __align__(16) _Float16 Ahs[128][64];
  __shared__ __align__(16) _Float16 Als[128][64];
  __shared__ __align__(16) _Float16 Bhs[128][64];
  __shared__ __align__(16) _Float16 Bls[128][64];

  const int z = blockIdx.z;
  const _Float16 *Ahg, *Alg, *Bhg, *Blg;
  _Float16 *yh, *yl;
  float scale; int three;
  if (z == 0)      { Ahg = xq_h; Alg = xq_l; Bhg = Wqh; Blg = Wql;
                     yh = qh_hi; yl = qh_lo; scale = QSCALE; three = 1; }
  else if (z == 1) { Ahg = xk_h; Alg = xk_l; Bhg = Wkh; Blg = Wkl;
                     yh = kh_hi; yl = kh_lo; scale = 1.0f; three = 1; }
  else             { Ahg = xv_h; Alg = xv_h; Bhg = Wvh; Blg = Wvh;
                     yh = vhT;   yl = vhT;   scale = 1.0f; three = 0; }

  const int tid = threadIdx.x;
  const int bm = blockIdx.x;          // 0..31
  const int bn = blockIdx.y;          // 0..7
  const int lane = tid & 63, l15 = lane & 15, quad = lane >> 4;
  const int w = tid >> 6, wm = w >> 1, wn = w & 1;

  // staging: wave w stages groups g = 4w+i (8 rows x 1 KiB each) of each array.
  // lane L: row-in-group = L>>3, fetches logical chunk (L&7)^(L>>3) -> XOR image.
  const int r8 = lane >> 3;
  const int cp8 = (((lane & 7) ^ r8)) * 8;    // half offset within row
  int grow[4]; _Float16* la[4]; _Float16* lal[4]; _Float16* lb[4]; _Float16* lbl[4];
  #pragma unroll
  for (int i = 0; i < 4; i++) {
    const int g = w * 4 + i;
    grow[i] = g * 8 + r8;                     // row 0..127 (per-lane)
    la[i]  = &Ahs[0][0] + g * 512;            // wave-uniform LDS bases
    lal[i] = &Als[0][0] + g * 512;
    lb[i]  = &Bhs[0][0] + g * 512;
    lbl[i] = &Bls[0][0] + g * 512;
  }

  floatx4 acc[4][4];
  #pragma unroll
  for (int mt = 0; mt < 4; mt++)
    #pragma unroll
    for (int nt = 0; nt < 4; nt++)
      acc[mt][nt] = (floatx4){0.f, 0.f, 0.f, 0.f};

  for (int kk = 0; kk < DM; kk += 64) {
    __syncthreads();                          // prior tile's reads complete
    #pragma unroll
    for (int i = 0; i < 4; i++) {
      const size_t ga = (size_t)(bm * 128 + grow[i]) * DM + kk + cp8;
      const size_t gb = (size_t)(bn * 128 + grow[i]) * DM + kk + cp8;
      gl2lds16(Ahg + ga, la[i]);
      gl2lds16(Bhg + gb, lb[i]);
      if (three) {
        gl2lds16(Alg + ga, lal[i]);
        gl2lds16(Blg + gb, lbl[i]);
      }
    }
    __syncthreads();                          // vmcnt(0) drain: tile visible

    #pragma unroll
    for (int kc = 0; kc < 2; kc++) {
      const int swz = ((kc * 4 + quad) ^ (l15 & 7)) * 8;
      half8 ah[4], bh_[4], al[4], bl[4];
      #pragma unroll
      for (int t = 0; t < 4; t++) {
        ah[t]  = *(const half8*)&Ahs[wm * 64 + t * 16 + l15][swz];
        bh_[t] = *(const half8*)&Bhs[wn * 64 + t * 16 + l15][swz];
        if (three) {
          al[t] = *(const half8*)&Als[wm * 64 + t * 16 + l15][swz];
          bl[t] = *(const half8*)&Bls[wn * 64 + t * 16 + l15][swz];
        }
      }
      if (three) {
        #pragma unroll
        for (int mt = 0; mt < 4; mt++)
          #pragma unroll
          for (int nt = 0; nt < 4; nt++) {
            floatx4 t0 = MFMA_F16(ah[mt], bh_[nt], acc[mt][nt]);
            t0 = MFMA_F16(ah[mt], bl[nt], t0);
            acc[mt][nt] = MFMA_F16(al[mt], bh_[nt], t0);
          }
      } else {
        #pragma unroll
        for (int mt = 0; mt < 4; mt++)
          #pragma unroll
          for (int nt = 0; nt < 4; nt++)
            acc[mt][nt] = MFMA_F16(ah[mt], bh_[nt], acc[mt][nt]);
      }
    }
  }

  if (three) {
    // Q/K epilogue: scalar hi/lo stores to [b,h,s,d]
    #pragma unroll
    for (int mt = 0; mt < 4; mt++)
      #pragma unroll
      for (int nt = 0; nt < 4; nt++)
        #pragma unroll
        for (int r = 0; r < 4; r++) {
          int gm = bm * 128 + wm * 64 + mt * 16 + quad * 4 + r;   // (b,s)
          int gn = bn * 128 + wn * 64 + nt * 16 + l15;            // h*64+d
          int b = gm >> 11, s = gm & 2047;
          int h = gn >> 6, d = gn & 63;
          size_t idx = ((size_t)(b * NH + h) * SEQ + s) * HD + d;
          float val = acc[mt][nt][r] * scale;
          _Float16 hi = (_Float16)val;
          yh[idx] = hi;
          yl[idx] = (_Float16)(val - (float)hi);
        }
  } else {
    // V epilogue: write vhT [bh][d][perm(s)] directly.
    // s = sbase + mt*16 + quad*4 + r ; s%32 = (mt&1)*16 + quad*4 + r
    // perm: 16a+4q+b -> 8q+4a+b, so pos = sbase + (mt>>1)*32 + quad*8 + (mt&1)*4 + r
    // r=0..3 contiguous -> one aligned half4 per (mt,nt).
    const int b = bm >> 4;
    const int h = bn * 2 + wn;
    const int bh = b * NH + h;
    const int sbase = (bm & 15) * 128 + wm * 64;
    _Float16* vt = vhT + (size_t)bh * HD * SEQ;
    #pragma unroll
    for (int mt = 0; mt < 4; mt++) {
      const int pos = sbase + (mt >> 1) * 32 + quad * 8 + (mt & 1) * 4;
      #pragma unroll
      for (int nt = 0; nt < 4; nt++) {
        const int d = nt * 16 + l15;
        half4 hv;
        hv[0] = (_Float16)acc[mt][nt][0];
        hv[1] = (_Float16)acc[mt][nt][1];
        hv[2] = (_Float16)acc[mt][nt][2];
        hv[3] = (_Float16)acc[mt][nt][3];
        *(half4*)(vt + (size_t)d * SEQ + pos) = hv;
      }
    }
  }
}

// ---------------- flash attention v12 (= R10): split-K x2 + 2-phase stage ---
// 1-D grid 1024; bh = (id&7) + 8*((id>>3)&3) pins each bh's K/V to one XCD L2.
// 4 waves, 32 q/wave. K hi/lo double-buffered, V single (40960 B LDS).
// Per kt: barrier -> stage V(kt)+K(kt+1) -> QK^T+softmax+pack -> barrier(drain)
// -> av reads + PV. (setprio removed: R11 showed -4% on this lockstep loop.)
__global__ __launch_bounds__(256, 4) void flash_kernel(
    const _Float16* __restrict__ qh_hi, const _Float16* __restrict__ qh_lo,
    const _Float16* __restrict__ kh_hi, const _Float16* __restrict__ kh_lo,
    const _Float16* __restrict__ vhT, float* __restrict__ Op, float2* __restrict__ ml)
{
  __shared__ __align__(16) _Float16 Kh[2][64][64];
  __shared__ __align__(16) _Float16 Kl[2][64][64];
  __shared__ __align__(16) _Float16 Vt[64][64];   // [d][permuted key]

  const int id = blockIdx.x;
  const int seq_ = id >> 3;
  const int bh = (id & 7) + 8 * (seq_ & 3);       // 0..31, pinned to XCD id&7
  const int rem = seq_ >> 2;
  const int qb = rem & 15;                        // 0..15
  const int kh = rem >> 4;                        // 0..1
  const int tid = threadIdx.x;
  const int wq = tid >> 6;
  const int lane = tid & 63, l15 = lane & 15, quad = lane >> 4;

  const size_t bh_off = (size_t)bh * SEQ * HD;
  const _Float16* __restrict__ kh_p = kh_hi + bh_off;
  const _Float16* __restrict__ kl_p = kh_lo + bh_off;
  const _Float16* __restrict__ vt_p = vhT + (size_t)bh * HD * SEQ;
  const int qrow0 = qb * 128 + wq * 32;

  // Q as B-operand fragments: lane holds n=q=l15, k=d=kc*32+quad*8+j
  half8 bqh[2][2], bql[2][2];         // [g][kc]
  #pragma unroll
  for (int g = 0; g < 2; g++) {
    const _Float16* qp_h = qh_hi + bh_off + (size_t)(qrow0 + g * 16 + l15) * HD;
    const _Float16* qp_l = qh_lo + bh_off + (size_t)(qrow0 + g * 16 + l15) * HD;
    #pragma unroll
    for (int kc = 0; kc < 2; kc++) {
      bqh[g][kc] = *(const half8*)(qp_h + kc * 32 + quad * 8);
      bql[g][kc] = *(const half8*)(qp_l + kc * 32 + quad * 8);
    }
  }

  // staging: wave wq covers groups 2wq, 2wq+1 per array (8 rows x 1 KiB each)
  const int r8 = lane >> 3;
  const int cp8 = ((lane & 7) ^ r8) * 8;

  float m_[2] = {-3.0e38f, -3.0e38f};
  float l_[2] = {0.f, 0.f};
  floatx4 Oacc[2][4];
  #pragma unroll
  for (int g = 0; g < 2; g++)
    #pragma unroll
    for (int nd = 0; nd < 4; nd++) Oacc[g][nd] = (floatx4){0.f, 0.f, 0.f, 0.f};

  const int kt0 = kh * 16;
  // prologue: stage K(kt0) into buffer 0
  {
    const int kbase = kt0 * 64;
    #pragma unroll
    for (int i = 0; i < 2; i++) {
      const int g = wq * 2 + i;
      const int r = g * 8 + r8;
      gl2lds16(kh_p + (size_t)(kbase + r) * HD + cp8, &Kh[0][0][0] + g * 512);
      gl2lds16(kl_p + (size_t)(kbase + r) * HD + cp8, &Kl[0][0][0] + g * 512);
    }
  }

  for (int kt = kt0; kt < kt0 + 16; kt++) {
    const int cur = kt & 1;                     // kt0 even -> prologue in buf 0
    const int kbase = kt * 64;
    __syncthreads();            // K(kt) visible; Vt free; Kbuf[cur^1] free

    // stage V(kt) and prefetch K(kt+1); both drain at the mid barrier below
    #pragma unroll
    for (int i = 0; i < 2; i++) {
      const int g = wq * 2 + i;
      const int r = g * 8 + r8;
      gl2lds16(vt_p + (size_t)r * SEQ + kbase + cp8, &Vt[0][0] + g * 512);
    }
    if (kt + 1 < kt0 + 16) {
      const int kb2 = (kt + 1) * 64, nxt = cur ^ 1;
      #pragma unroll
      for (int i = 0; i < 2; i++) {
        const int g = wq * 2 + i;
        const int r = g * 8 + r8;
        gl2lds16(kh_p + (size_t)(kb2 + r) * HD + cp8, &Kh[nxt][0][0] + g * 512);
        gl2lds16(kl_p + (size_t)(kb2 + r) * HD + cp8, &Kl[nxt][0][0] + g * 512);
      }
    }

    // S^T = K·Q^T (3-term split fp16), both q-groups share K fragments
    floatx4 sacc[2][4];
    const int r7 = l15 & 7;
    #pragma unroll
    for (int nt = 0; nt < 4; nt++) {
      half8 akh0 = *(const half8*)&Kh[cur][nt * 16 + l15][((0 * 4 + quad) ^ r7) * 8];
      half8 akh1 = *(const half8*)&Kh[cur][nt * 16 + l15][((1 * 4 + quad) ^ r7) * 8];
      half8 akl0 = *(const half8*)&Kl[cur][nt * 16 + l15][((0 * 4 + quad) ^ r7) * 8];
      half8 akl1 = *(const half8*)&Kl[cur][nt * 16 + l15][((1 * 4 + quad) ^ r7) * 8];
      #pragma unroll
      for (int g = 0; g < 2; g++) {
        floatx4 s4 = (floatx4){0.f, 0.f, 0.f, 0.f};
        s4 = MFMA_F16(akh0, bqh[g][0], s4);
        s4 = MFMA_F16(akh1, bqh[g][1], s4);
        s4 = MFMA_F16(akh0, bql[g][0], s4);
        s4 = MFMA_F16(akh1, bql[g][1], s4);
        s4 = MFMA_F16(akl0, bqh[g][0], s4);
        s4 = MFMA_F16(akl1, bqh[g][1], s4);
        sacc[g][nt] = s4;
      }
    }

    // online softmax + P pack for BOTH q-groups (before the drain barrier)
    float alpha2[2];
    half8 bp8g[2][2];
    #pragma unroll
    for (int g = 0; g < 2; g++) {
      float rmax = sacc[g][0][0];
      #pragma unroll
      for (int nt = 0; nt < 4; nt++)
        #pragma unroll
        for (int r = 0; r < 4; r++) rmax = fmaxf(rmax, sacc[g][nt][r]);
      rmax = fmaxf(rmax, __shfl_xor(rmax, 16, 64));
      rmax = fmaxf(rmax, __shfl_xor(rmax, 32, 64));
      const float mnew = fmaxf(m_[g], rmax);
      alpha2[g] = exp2f(m_[g] - mnew);
      m_[g] = mnew;

      float rsum = 0.f;
      #pragma unroll
      for (int nt = 0; nt < 4; nt++)
        #pragma unroll
        for (int r = 0; r < 4; r++) {
          float p = exp2f(sacc[g][nt][r] - mnew);
          sacc[g][nt][r] = p;
          rsum += p;
        }
      rsum += __shfl_xor(rsum, 16, 64);
      rsum += __shfl_xor(rsum, 32, 64);
      l_[g] = l_[g] * alpha2[g] + rsum;

      // P pack for PV B-operand: bp8g[g][kc][j] = p[2kc + (j>>2)][j&3] (in-lane)
      #pragma unroll
      for (int kc = 0; kc < 2; kc++)
        #pragma unroll
        for (int j = 0; j < 8; j++)
          bp8g[g][kc][j] = (_Float16)sacc[g][2 * kc + (j >> 2)][j & 3];
    }

    __syncthreads();            // V(kt) + K(kt+1) drained & visible

    // V A-fragments (permuted image), shared by both q-groups
    half8 av[4][2];
    #pragma unroll
    for (int nd = 0; nd < 4; nd++) {
      av[nd][0] = *(const half8*)&Vt[nd * 16 + l15][((0 * 4 + quad) ^ r7) * 8];
      av[nd][1] = *(const half8*)&Vt[nd * 16 + l15][((1 * 4 + quad) ^ r7) * 8];
    }

    #pragma unroll
    for (int g = 0; g < 2; g++) {
      #pragma unroll
      for (int nd = 0; nd < 4; nd++) {
        Oacc[g][nd][0] *= alpha2[g]; Oacc[g][nd][1] *= alpha2[g];
        Oacc[g][nd][2] *= alpha2[g]; Oacc[g][nd][3] *= alpha2[g];
        Oacc[g][nd] = MFMA_F16(av[nd][0], bp8g[g][0], Oacc[g][nd]);
        Oacc[g][nd] = MFMA_F16(av[nd][1], bp8g[g][1], Oacc[g][nd]);
      }
    }
  }

  // epilogue: unnormalized O^T partial + (m,l)
  const size_t fqbase = (size_t)bh * SEQ + qrow0;
  #pragma unroll
  for (int g = 0; g < 2; g++) {
    const size_t fq = fqbase + g * 16 + l15;
    float* ob = Op + ((size_t)kh * 65536 + fq) * HD;
    #pragma unroll
    for (int nd = 0; nd < 4; nd++) {
      float4 vv;
      vv.x = Oacc[g][nd][0]; vv.y = Oacc[g][nd][1];
      vv.z = Oacc[g][nd][2]; vv.w = Oacc[g][nd][3];
      *(float4*)(ob + nd * 16 + quad * 4) = vv;
    }
    if (quad == 0) ml[kh * 65536 + fq] = make_float2(m_[g], l_[g]);
  }
}

// ---------------- merge the two split-K partials ----------------
__global__ __launch_bounds__(256) void merge_kernel(const float* __restrict__ Op,
                                                    const float2* __restrict__ ml,
                                                    float* __restrict__ out)
{
  const int tid = threadIdx.x;
  const int fq = blockIdx.x * 64 + (tid >> 2);
  const int dp = (tid & 3) * 16;
  float2 m0 = ml[fq], m1 = ml[65536 + fq];
  float M = fmaxf(m0.x, m1.x);
  float w0 = exp2f(m0.x - M), w1 = exp2f(m1.x - M);
  float rinv = 1.0f / (m0.y * w0 + m1.y * w1);
  int bh = fq >> 11, s = fq & 2047, b = bh >> 4, h = bh & 15;
  float* ob = out + ((size_t)(b * SEQ + s)) * DM + h * HD + dp;
  const float* p0 = Op + (size_t)fq * HD + dp;
  const float* p1 = p0 + (size_t)65536 * HD;
  #pragma unroll
  for (int j = 0; j < 4; j++) {
    float4 a = *(const float4*)(p0 + 4 * j);
    float4 c = *(const float4*)(p1 + 4 * j);
    float4 r;
    r.x = (a.x * w0 + c.x * w1) * rinv;
    r.y = (a.y * w0 + c.y * w1) * rinv;
    r.z = (a.z * w0 + c.z * w1) * rinv;
    r.w = (a.w * w0 + c.w * w1) * rinv;
    *(float4*)(ob + 4 * j) = r;
  }
}

extern "C" void kernel_launch(void* const* d_in, const int* in_sizes, int n_in,
                              void* d_out, int out_size, void* d_ws, size_t ws_size,
                              hipStream_t stream) {
  const float* q  = (const float*)d_in[0];
  const float* k  = (const float*)d_in[1];
  const float* v  = (const float*)d_in[2];
  const float* Wq = (const float*)d_in[3];
  const float* Wk = (const float*)d_in[4];
  const float* Wv = (const float*)d_in[5];
  float* out = (float*)d_out;

  char* W = (char*)d_ws;
  const size_t MiB = 1ull << 20;
  _Float16* qh_hi = (_Float16*)(W + 0 * MiB);
  _Float16* qh_lo = (_Float16*)(W + 8 * MiB);
  _Float16* kh_hi = (_Float16*)(W + 16 * MiB);
  _Float16* kh_lo = (_Float16*)(W + 24 * MiB);
  _Float16* vhT   = (_Float16*)(W + 32 * MiB);
  _Float16* xq_h  = (_Float16*)(W + 48 * MiB);  // dead after proj3
  _Float16* xq_l  = (_Float16*)(W + 56 * MiB);
  _Float16* xk_h  = (_Float16*)(W + 64 * MiB);
  _Float16* xk_l  = (_Float16*)(W + 72 * MiB);
  _Float16* xv_h  = (_Float16*)(W + 80 * MiB);
  _Float16* Wqh   = (_Float16*)(W + 88 * MiB);
  _Float16* Wql   = (_Float16*)(W + 90 * MiB);
  _Float16* Wkh   = (_Float16*)(W + 92 * MiB);
  _Float16* Wkl   = (_Float16*)(W + 94 * MiB);
  _Float16* Wvh   = (_Float16*)(W + 96 * MiB);
  float*    Op    = (float*)  (W + 40 * MiB);   // 2 x 16 MiB, aliases xq slots (dead)
  float2*   mlp   = (float2*) (W + 98 * MiB);   // 1 MiB; total 99 MiB

  convert_all<<<15360, 256, 0, stream>>>(q, k, v, Wq, Wk, Wv,
                                         xq_h, xq_l, xk_h, xk_l, xv_h,
                                         Wqh, Wql, Wkh, Wkl, Wvh);
  proj3_kernel<<<dim3(32, 8, 3), 256, 0, stream>>>(
      xq_h, xq_l, xk_h, xk_l, xv_h, Wqh, Wql, Wkh, Wkl, Wvh,
      qh_hi, qh_lo, kh_hi, kh_lo, vhT);
  flash_kernel<<<1024, 256, 0, stream>>>(qh_hi, qh_lo, kh_hi, kh_lo, vhT, Op, mlp);
  merge_kernel<<<1024, 256, 0, stream>>>(Op, mlp, out);
}